// Round 1
// baseline (1529.897 us; speedup 1.0000x reference)
//
#include <hip/hip_runtime.h>

typedef __bf16 bf16_t;
typedef __bf16 bf16x8 __attribute__((ext_vector_type(8)));
typedef __bf16 bf16x4 __attribute__((ext_vector_type(4)));
typedef float  f32x4  __attribute__((ext_vector_type(4)));

#define MFMA16(a,b,c) __builtin_amdgcn_mfma_f32_16x16x32_bf16((a),(b),(c),0,0,0)

constexpr int NNODES = 32768;
constexpr int NEDGES = 262144;
constexpr int DD = 128;
constexpr int DE = 64;
constexpr int HH = 256;
constexpr int KIN = 320;   // 2*D + DE

__device__ __forceinline__ bf16x8 cvt8(f32x4 a, f32x4 b){
  bf16x8 r;
  r[0]=(bf16_t)a[0]; r[1]=(bf16_t)a[1]; r[2]=(bf16_t)a[2]; r[3]=(bf16_t)a[3];
  r[4]=(bf16_t)b[0]; r[5]=(bf16_t)b[1]; r[6]=(bf16_t)b[2]; r[7]=(bf16_t)b[3];
  return r;
}

__global__ void cvt_kernel(const float* __restrict__ in, bf16_t* __restrict__ out, int n){
  int i = (blockIdx.x*256 + threadIdx.x)*4;
  if (i < n){
    f32x4 v = *(const f32x4*)(in + i);
    bf16x4 o; o[0]=(bf16_t)v[0]; o[1]=(bf16_t)v[1]; o[2]=(bf16_t)v[2]; o[3]=(bf16_t)v[3];
    *(bf16x4*)(out + i) = o;
  }
}

// ---------------- edge MLPs + scatter-add ----------------
__global__ __launch_bounds__(256,2) void edge_mlp_kernel(
    const float* __restrict__ ns, const float* __restrict__ ef,
    const int* __restrict__ from_idx, const int* __restrict__ to_idx,
    const bf16_t* __restrict__ Wm1b, const float* __restrict__ bm1,
    const bf16_t* __restrict__ Wm2b, const float* __restrict__ bm2,
    const bf16_t* __restrict__ Wr1b, const float* __restrict__ br1,
    const bf16_t* __restrict__ Wr2b, const float* __restrict__ br2,
    float* __restrict__ agg)
{
  constexpr int XS = 328;   // padded row stride (bf16) for X = [fs|ts|ef]
  constexpr int HS = 264;   // padded row stride for hidden
  __shared__ bf16_t Xs[64*XS];
  __shared__ bf16_t Hs[64*HS];
  const int tid = threadIdx.x;
  const int eb = blockIdx.x * 64;

  // stage X (64 edges x 320 cols) as bf16: 4 threads per edge row
  {
    const int row  = tid >> 2;
    const int part = tid & 3;
    const int e = eb + row;
    const float* __restrict__ s0 = ns + (size_t)from_idx[e]*DD;
    const float* __restrict__ s1 = ns + (size_t)to_idx[e]*DD;
    const float* __restrict__ s2 = ef + (size_t)e*DE;
    #pragma unroll
    for (int j=0;j<20;j++){
      int c4 = part*80 + j*4;
      const float* s; int off;
      if (c4 < 128){ s=s0; off=c4; }
      else if (c4 < 256){ s=s1; off=c4-128; }
      else { s=s2; off=c4-256; }
      f32x4 v = *(const f32x4*)(s+off);
      bf16x4 o; o[0]=(bf16_t)v[0]; o[1]=(bf16_t)v[1]; o[2]=(bf16_t)v[2]; o[3]=(bf16_t)v[3];
      *(bf16x4*)&Xs[row*XS + c4] = o;
    }
  }
  __syncthreads();

  const int lane = tid & 63;
  const int wave = tid >> 6;
  const int lr = lane & 15;   // A-row / B-col within tile
  const int lk = lane >> 4;   // k sub-group (0..3)

  #pragma unroll
  for (int dir=0; dir<2; ++dir){
    const bf16_t* __restrict__ W1 = dir ? Wr1b : Wm1b;
    const bf16_t* __restrict__ W2 = dir ? Wr2b : Wm2b;
    const float*  __restrict__ b1 = dir ? br1 : bm1;
    const float*  __restrict__ b2 = dir ? br2 : bm2;
    const int*    __restrict__ didx = dir ? from_idx : to_idx;

    // -------- layer 1: [64x320] @ W1^T -> [64x256] --------
    f32x4 acc[16];
    #pragma unroll
    for (int nt=0;nt<16;nt++) acc[nt] = (f32x4){0.f,0.f,0.f,0.f};
    #pragma unroll
    for (int kc=0;kc<10;kc++){
      // rev MLP input is [ts|fs|ef]: swap the first two 128-col blocks
      const int kcx = dir ? ((kc<4)?(kc+4):((kc<8)?(kc-4):kc)) : kc;
      bf16x8 a = *(const bf16x8*)&Xs[(wave*16 + lr)*XS + kcx*32 + lk*8];
      #pragma unroll
      for (int nt=0;nt<16;nt++){
        bf16x8 b = *(const bf16x8*)&W1[(size_t)(nt*16 + lr)*KIN + kc*32 + lk*8];
        acc[nt] = MFMA16(a,b,acc[nt]);
      }
    }
    // relu + bias -> Hs (bf16), per-wave rows
    #pragma unroll
    for (int nt=0;nt<16;nt++){
      float bias = b1[nt*16 + lr];
      #pragma unroll
      for (int r=0;r<4;r++){
        float v = acc[nt][r] + bias;
        v = v > 0.f ? v : 0.f;
        Hs[(wave*16 + lk*4 + r)*HS + nt*16 + lr] = (bf16_t)v;
      }
    }
    asm volatile("s_waitcnt lgkmcnt(0)" ::: "memory");
    __builtin_amdgcn_sched_barrier(0);

    // -------- layer 2: [64x256] @ W2^T -> [64x256] --------
    f32x4 acc2[16];
    #pragma unroll
    for (int nt=0;nt<16;nt++) acc2[nt] = (f32x4){0.f,0.f,0.f,0.f};
    #pragma unroll
    for (int kc=0;kc<8;kc++){
      bf16x8 a = *(const bf16x8*)&Hs[(wave*16 + lr)*HS + kc*32 + lk*8];
      #pragma unroll
      for (int nt=0;nt<16;nt++){
        bf16x8 b = *(const bf16x8*)&W2[(size_t)(nt*16 + lr)*HH + kc*32 + lk*8];
        acc2[nt] = MFMA16(a,b,acc2[nt]);
      }
    }
    // bias + scatter-add into agg
    const int e0 = eb + wave*16 + lk*4;
    int di[4];
    #pragma unroll
    for (int r=0;r<4;r++) di[r] = didx[e0+r];
    #pragma unroll
    for (int nt=0;nt<16;nt++){
      float bias = b2[nt*16 + lr];
      #pragma unroll
      for (int r=0;r<4;r++){
        atomicAdd(agg + (size_t)di[r]*HH + nt*16 + lr, acc2[nt][r] + bias);
      }
    }
  }
}

// ---------------- cross-graph attention (flash style) ----------------
__global__ __launch_bounds__(256,2) void attn_kernel(
    const float* __restrict__ ns, float* __restrict__ attn)
{
  constexpr int KS = 136;  // K tile row stride (bf16)
  constexpr int VS = 40;   // V^T / P row stride (bf16)
  __shared__ bf16_t Ks[32*KS];
  __shared__ bf16_t Vt[128*VS];
  __shared__ bf16_t Ps[64*VS];
  const int tid = threadIdx.x;
  const int lane = tid & 63, wave = tid >> 6, lr = lane & 15, lk = lane >> 4;
  const int bx = blockIdx.x;
  const int qt = bx & 31, side = (bx>>5)&1, p = bx>>6;
  const size_t qbase  = (size_t)p*4096 + (size_t)side*2048 + (size_t)qt*64;
  const size_t kvbase = (size_t)p*4096 + (size_t)(side^1)*2048;

  // hoist Q fragments (16 q-rows per wave, D=128 -> 4 k-chunks)
  bf16x8 qf[4];
  {
    const float* qrow = ns + (qbase + wave*16 + lr)*DD;
    #pragma unroll
    for (int kc=0;kc<4;kc++){
      f32x4 v0 = *(const f32x4*)(qrow + kc*32 + lk*8);
      f32x4 v1 = *(const f32x4*)(qrow + kc*32 + lk*8 + 4);
      qf[kc] = cvt8(v0,v1);
    }
  }
  float m0[4], ls[4];
  #pragma unroll
  for (int r=0;r<4;r++){ m0[r] = -3.0e38f; ls[r] = 0.f; }
  f32x4 acco[8];
  #pragma unroll
  for (int nt=0;nt<8;nt++) acco[nt]=(f32x4){0.f,0.f,0.f,0.f};

  for (int kt=0; kt<64; ++kt){
    __syncthreads();
    { // stage K (row-major) and V^T (transposed) as bf16
      const int row = tid >> 3;
      const int c0  = (tid & 7)*16;
      const float* src = ns + (kvbase + (size_t)kt*32 + row)*DD + c0;
      #pragma unroll
      for (int j=0;j<4;j++){
        f32x4 v = *(const f32x4*)(src + j*4);
        bf16x4 o; o[0]=(bf16_t)v[0]; o[1]=(bf16_t)v[1]; o[2]=(bf16_t)v[2]; o[3]=(bf16_t)v[3];
        *(bf16x4*)&Ks[row*KS + c0 + j*4] = o;
        Vt[(c0+j*4+0)*VS + row] = o[0];
        Vt[(c0+j*4+1)*VS + row] = o[1];
        Vt[(c0+j*4+2)*VS + row] = o[2];
        Vt[(c0+j*4+3)*VS + row] = o[3];
      }
    }
    __syncthreads();

    // S = Q K^T  (16 q-rows x 32 kv)
    f32x4 s0 = (f32x4){0.f,0.f,0.f,0.f}, s1 = (f32x4){0.f,0.f,0.f,0.f};
    #pragma unroll
    for (int kc=0;kc<4;kc++){
      bf16x8 b0 = *(const bf16x8*)&Ks[lr*KS       + kc*32 + lk*8];
      bf16x8 b1 = *(const bf16x8*)&Ks[(16+lr)*KS  + kc*32 + lk*8];
      s0 = MFMA16(qf[kc], b0, s0);
      s1 = MFMA16(qf[kc], b1, s1);
    }
    // online softmax per q-row (row i = lk*4+r lives in the 16-lane group)
    #pragma unroll
    for (int r=0;r<4;r++){
      float mr = fmaxf(s0[r], s1[r]);
      mr = fmaxf(mr, __shfl_xor(mr, 1));
      mr = fmaxf(mr, __shfl_xor(mr, 2));
      mr = fmaxf(mr, __shfl_xor(mr, 4));
      mr = fmaxf(mr, __shfl_xor(mr, 8));
      const float mnew  = fmaxf(m0[r], mr);
      const float scale = __expf(m0[r] - mnew);
      m0[r] = mnew;
      const float p0 = __expf(s0[r] - mnew);
      const float p1 = __expf(s1[r] - mnew);
      float rs = p0 + p1;
      rs += __shfl_xor(rs, 1);
      rs += __shfl_xor(rs, 2);
      rs += __shfl_xor(rs, 4);
      rs += __shfl_xor(rs, 8);
      ls[r] = ls[r]*scale + rs;
      #pragma unroll
      for (int nt=0;nt<8;nt++) acco[nt][r] *= scale;
      Ps[(wave*16 + lk*4 + r)*VS + lr]      = (bf16_t)p0;
      Ps[(wave*16 + lk*4 + r)*VS + 16 + lr] = (bf16_t)p1;
    }
    asm volatile("s_waitcnt lgkmcnt(0)" ::: "memory");
    __builtin_amdgcn_sched_barrier(0);
    // O += P V   (P: 16x32, V: 32x128)
    bf16x8 pa = *(const bf16x8*)&Ps[(wave*16 + lr)*VS + lk*8];
    #pragma unroll
    for (int nt=0;nt<8;nt++){
      bf16x8 vb = *(const bf16x8*)&Vt[(nt*16+lr)*VS + lk*8];
      acco[nt] = MFMA16(pa, vb, acco[nt]);
    }
  }
  // epilogue: attn_input = ns - O/l
  float inv[4];
  #pragma unroll
  for (int r=0;r<4;r++) inv[r] = 1.f/ls[r];
  #pragma unroll
  for (int nt=0;nt<8;nt++){
    const int col = nt*16 + lr;
    #pragma unroll
    for (int r=0;r<4;r++){
      const size_t row = qbase + wave*16 + lk*4 + r;
      attn[row*DD + col] = ns[row*DD + col] - acco[nt][r]*inv[r];
    }
  }
}

// ---------------- node MLP + residual ----------------
__global__ __launch_bounds__(256,2) void node_mlp_kernel(
    const float* __restrict__ agg, const float* __restrict__ attn,
    const float* __restrict__ ns,
    const bf16_t* __restrict__ Wn1b, const float* __restrict__ bn1,
    const bf16_t* __restrict__ Wn2b, const float* __restrict__ bn2,
    float* __restrict__ out)
{
  constexpr int HS = 264;
  __shared__ bf16_t Hs[64*HS];
  const int tid = threadIdx.x;
  const int lane = tid & 63, wave = tid >> 6, lr = lane & 15, lk = lane >> 4;
  const int rb = blockIdx.x*64;
  const int row = rb + wave*16 + lr;

  // layer 1: K=512 from [agg(256) | attn(128) | ns(128)] (fp32 -> bf16 in reg)
  f32x4 acc[16];
  #pragma unroll
  for (int nt=0;nt<16;nt++) acc[nt] = (f32x4){0.f,0.f,0.f,0.f};
  #pragma unroll
  for (int kc=0;kc<16;kc++){
    const float* s; int col;
    if (kc < 8)      { s = agg  + (size_t)row*HH; col = kc*32 + lk*8; }
    else if (kc <12) { s = attn + (size_t)row*DD; col = kc*32 + lk*8 - 256; }
    else             { s = ns   + (size_t)row*DD; col = kc*32 + lk*8 - 384; }
    f32x4 v0 = *(const f32x4*)(s + col);
    f32x4 v1 = *(const f32x4*)(s + col + 4);
    bf16x8 a = cvt8(v0,v1);
    #pragma unroll
    for (int nt=0;nt<16;nt++){
      bf16x8 b = *(const bf16x8*)&Wn1b[(size_t)(nt*16 + lr)*512 + kc*32 + lk*8];
      acc[nt] = MFMA16(a,b,acc[nt]);
    }
  }
  #pragma unroll
  for (int nt=0;nt<16;nt++){
    float bias = bn1[nt*16 + lr];
    #pragma unroll
    for (int r=0;r<4;r++){
      float v = acc[nt][r] + bias;
      v = v > 0.f ? v : 0.f;
      Hs[(wave*16 + lk*4 + r)*HS + nt*16 + lr] = (bf16_t)v;
    }
  }
  asm volatile("s_waitcnt lgkmcnt(0)" ::: "memory");
  __builtin_amdgcn_sched_barrier(0);

  // layer 2: K=256 -> N=128, + bn2 + residual
  f32x4 acc2[8];
  #pragma unroll
  for (int nt=0;nt<8;nt++) acc2[nt] = (f32x4){0.f,0.f,0.f,0.f};
  #pragma unroll
  for (int kc=0;kc<8;kc++){
    bf16x8 a = *(const bf16x8*)&Hs[(wave*16 + lr)*HS + kc*32 + lk*8];
    #pragma unroll
    for (int nt=0;nt<8;nt++){
      bf16x8 b = *(const bf16x8*)&Wn2b[(size_t)(nt*16 + lr)*HH + kc*32 + lk*8];
      acc2[nt] = MFMA16(a,b,acc2[nt]);
    }
  }
  const int r0 = rb + wave*16 + lk*4;
  #pragma unroll
  for (int nt=0;nt<8;nt++){
    const int col = nt*16 + lr;
    const float bias = bn2[col];
    #pragma unroll
    for (int r=0;r<4;r++){
      const size_t rr = (size_t)(r0 + r);
      out[rr*DD + col] = acc2[nt][r] + bias + ns[rr*DD + col];
    }
  }
}

extern "C" void kernel_launch(void* const* d_in, const int* in_sizes, int n_in,
                              void* d_out, int out_size, void* d_ws, size_t ws_size,
                              hipStream_t stream) {
  const float* ns  = (const float*)d_in[0];
  const float* ef  = (const float*)d_in[1];
  const int* from_idx = (const int*)d_in[2];
  const int* to_idx   = (const int*)d_in[3];
  // d_in[4] graph_idx, d_in[5] n_graphs: unused (static sizes)
  const float* Wm1 = (const float*)d_in[6];  const float* bm1 = (const float*)d_in[7];
  const float* Wm2 = (const float*)d_in[8];  const float* bm2 = (const float*)d_in[9];
  const float* Wr1 = (const float*)d_in[10]; const float* br1 = (const float*)d_in[11];
  const float* Wr2 = (const float*)d_in[12]; const float* br2 = (const float*)d_in[13];
  const float* Wn1 = (const float*)d_in[14]; const float* bn1 = (const float*)d_in[15];
  const float* Wn2 = (const float*)d_in[16]; const float* bn2 = (const float*)d_in[17];

  char* ws = (char*)d_ws;
  float* agg   = (float*)ws;                          // 32768*256*4 = 32MB
  float* attn  = (float*)(ws + 33554432);             // 32768*128*4 = 16MB
  bf16_t* wm1b = (bf16_t*)(ws + 50331648);            // 81920*2
  bf16_t* wm2b = (bf16_t*)(ws + 50495488);            // 65536*2
  bf16_t* wr1b = (bf16_t*)(ws + 50626560);            // 81920*2
  bf16_t* wr2b = (bf16_t*)(ws + 50790400);            // 65536*2
  bf16_t* wn1b = (bf16_t*)(ws + 50921472);            // 131072*2
  bf16_t* wn2b = (bf16_t*)(ws + 51183616);            // 32768*2

  hipMemsetAsync(agg, 0, (size_t)NNODES*HH*sizeof(float), stream);

  cvt_kernel<<<80, 256, 0, stream>>>(Wm1, wm1b, 256*320);
  cvt_kernel<<<64, 256, 0, stream>>>(Wm2, wm2b, 256*256);
  cvt_kernel<<<80, 256, 0, stream>>>(Wr1, wr1b, 256*320);
  cvt_kernel<<<64, 256, 0, stream>>>(Wr2, wr2b, 256*256);
  cvt_kernel<<<128,256, 0, stream>>>(Wn1, wn1b, 256*512);
  cvt_kernel<<<32, 256, 0, stream>>>(Wn2, wn2b, 128*256);

  edge_mlp_kernel<<<NEDGES/64, 256, 0, stream>>>(ns, ef, from_idx, to_idx,
      wm1b, bm1, wm2b, bm2, wr1b, br1, wr2b, br2, agg);

  attn_kernel<<<512, 256, 0, stream>>>(ns, attn);

  node_mlp_kernel<<<NNODES/64, 256, 0, stream>>>(agg, attn, ns,
      wn1b, bn1, wn2b, bn2, (float*)d_out);
}

// Round 2
// 1268.500 us; speedup vs baseline: 1.2061x; 1.2061x over previous
//
#include <hip/hip_runtime.h>

typedef __bf16 bf16_t;
typedef __bf16 bf16x8 __attribute__((ext_vector_type(8)));
typedef __bf16 bf16x4 __attribute__((ext_vector_type(4)));
typedef float  f32x4  __attribute__((ext_vector_type(4)));

#define MFMA16(a,b,c) __builtin_amdgcn_mfma_f32_16x16x32_bf16((a),(b),(c),0,0,0)

constexpr int NNODES = 32768;
constexpr int NEDGES = 262144;
constexpr int DD = 128;
constexpr int DE = 64;
constexpr int HH = 256;
constexpr int KIN = 320;   // 2*D + DE

__device__ __forceinline__ bf16x8 cvt8(f32x4 a, f32x4 b){
  bf16x8 r;
  r[0]=(bf16_t)a[0]; r[1]=(bf16_t)a[1]; r[2]=(bf16_t)a[2]; r[3]=(bf16_t)a[3];
  r[4]=(bf16_t)b[0]; r[5]=(bf16_t)b[1]; r[6]=(bf16_t)b[2]; r[7]=(bf16_t)b[3];
  return r;
}

__global__ void cvt_kernel(const float* __restrict__ in, bf16_t* __restrict__ out, int n){
  int i = (blockIdx.x*256 + threadIdx.x)*4;
  if (i < n){
    f32x4 v = *(const f32x4*)(in + i);
    bf16x4 o; o[0]=(bf16_t)v[0]; o[1]=(bf16_t)v[1]; o[2]=(bf16_t)v[2]; o[3]=(bf16_t)v[3];
    *(bf16x4*)(out + i) = o;
  }
}

// ---------------- CSR build ----------------
__global__ void hist_kernel(const int* __restrict__ to_idx, const int* __restrict__ from_idx,
                            int* __restrict__ cnt_to, int* __restrict__ cnt_from){
  int e = blockIdx.x*256 + threadIdx.x;
  if (e < NEDGES){
    atomicAdd(&cnt_to[to_idx[e]], 1);
    atomicAdd(&cnt_from[from_idx[e]], 1);
  }
}

// single block, 1024 threads; exclusive scan of cnt[0..32767] -> start[0..32768],
// and cnt is overwritten in-place with the same prefix (used as placement cursor).
__global__ void scan_kernel(int* __restrict__ cnt, int* __restrict__ start){
  __shared__ int sums[1024];
  const int t = threadIdx.x;
  int local[32]; int s = 0;
  #pragma unroll
  for (int j=0;j<32;j++){ local[j] = cnt[t*32+j]; s += local[j]; }
  sums[t] = s; __syncthreads();
  #pragma unroll
  for (int d=1; d<1024; d<<=1){
    int v = (t>=d) ? sums[t-d] : 0;
    __syncthreads();
    sums[t] += v;
    __syncthreads();
  }
  int off = sums[t] - s;  // exclusive prefix of this thread's chunk
  #pragma unroll
  for (int j=0;j<32;j++){
    start[t*32+j] = off;
    cnt[t*32+j]   = off;
    off += local[j];
  }
  if (t == 1023) start[32768] = sums[1023];
}

__global__ void place_kernel(const int* __restrict__ to_idx, const int* __restrict__ from_idx,
                             int* __restrict__ cur_to, int* __restrict__ cur_from,
                             int* __restrict__ eid_to, int* __restrict__ eid_from){
  int e = blockIdx.x*256 + threadIdx.x;
  if (e < NEDGES){
    int p = atomicAdd(&cur_to[to_idx[e]], 1);
    eid_to[p] = e;
    int q = atomicAdd(&cur_from[from_idx[e]], 1);
    eid_from[q] = e;
  }
}

// ---------------- edge MLP layer-1 only -> h (bf16, edge order) ----------------
__global__ __launch_bounds__(256,3) void edge_h_kernel(
    const float* __restrict__ ns, const float* __restrict__ ef,
    const int* __restrict__ from_idx, const int* __restrict__ to_idx,
    const bf16_t* __restrict__ W1, const float* __restrict__ b1,
    bf16_t* __restrict__ msg, int swap)
{
  constexpr int XS = 328;   // padded row stride (bf16) for X = [fs|ts|ef]
  __shared__ bf16_t Xs[64*XS];   // 41,984 B
  const int tid = threadIdx.x;
  const int eb = blockIdx.x * 64;

  { // stage X (64 edges x 320 cols) as bf16: 4 threads per edge row
    const int row  = tid >> 2;
    const int part = tid & 3;
    const int e = eb + row;
    const float* __restrict__ s0 = ns + (size_t)from_idx[e]*DD;
    const float* __restrict__ s1 = ns + (size_t)to_idx[e]*DD;
    const float* __restrict__ s2 = ef + (size_t)e*DE;
    #pragma unroll
    for (int j=0;j<20;j++){
      int c4 = part*80 + j*4;
      const float* s; int off;
      if (c4 < 128){ s=s0; off=c4; }
      else if (c4 < 256){ s=s1; off=c4-128; }
      else { s=s2; off=c4-256; }
      f32x4 v = *(const f32x4*)(s+off);
      bf16x4 o; o[0]=(bf16_t)v[0]; o[1]=(bf16_t)v[1]; o[2]=(bf16_t)v[2]; o[3]=(bf16_t)v[3];
      *(bf16x4*)&Xs[row*XS + c4] = o;
    }
  }
  __syncthreads();

  const int lane = tid & 63;
  const int wave = tid >> 6;
  const int lr = lane & 15;
  const int lk = lane >> 4;

  f32x4 acc[16];
  #pragma unroll
  for (int nt=0;nt<16;nt++) acc[nt] = (f32x4){0.f,0.f,0.f,0.f};
  #pragma unroll
  for (int kc=0;kc<10;kc++){
    // rev MLP input is [ts|fs|ef]: swap the first two 128-col blocks
    const int kcx = swap ? ((kc<4)?(kc+4):((kc<8)?(kc-4):kc)) : kc;
    bf16x8 a = *(const bf16x8*)&Xs[(wave*16 + lr)*XS + kcx*32 + lk*8];
    #pragma unroll
    for (int nt=0;nt<16;nt++){
      bf16x8 b = *(const bf16x8*)&W1[(size_t)(nt*16 + lr)*KIN + kc*32 + lk*8];
      acc[nt] = MFMA16(a,b,acc[nt]);
    }
  }
  // relu + bias -> msg (bf16, edge order)
  #pragma unroll
  for (int nt=0;nt<16;nt++){
    float bias = b1[nt*16 + lr];
    #pragma unroll
    for (int r=0;r<4;r++){
      float v = acc[nt][r] + bias;
      v = v > 0.f ? v : 0.f;
      msg[(size_t)(eb + wave*16 + lk*4 + r)*HH + nt*16 + lr] = (bf16_t)v;
    }
  }
}

// ---------------- per-node gather-sum of h (f64 accum -> deterministic) ----------------
__global__ __launch_bounds__(256) void agg_h_kernel(
    const bf16_t* __restrict__ msg, const int* __restrict__ start,
    const int* __restrict__ eid, bf16_t* __restrict__ aggh)
{
  const int wave = threadIdx.x >> 6;
  const int lane = threadIdx.x & 63;
  const int v = blockIdx.x*4 + wave;
  const int s = start[v], e = start[v+1];
  double acc0=0, acc1=0, acc2=0, acc3=0;
  for (int i=s; i<e; ++i){
    const int eg = eid[i];
    bf16x4 h = *(const bf16x4*)&msg[(size_t)eg*HH + lane*4];
    acc0 += (float)h[0]; acc1 += (float)h[1];
    acc2 += (float)h[2]; acc3 += (float)h[3];
  }
  bf16x4 o;
  o[0]=(bf16_t)(float)acc0; o[1]=(bf16_t)(float)acc1;
  o[2]=(bf16_t)(float)acc2; o[3]=(bf16_t)(float)acc3;
  *(bf16x4*)&aggh[(size_t)v*HH + lane*4] = o;
}

// ---------------- agg = aggh_f @ Wm2^T + deg_to*bm2 + aggh_r @ Wr2^T + deg_from*br2 ----------------
__global__ __launch_bounds__(256,2) void agg_gemm_kernel(
    const bf16_t* __restrict__ aggh_f, const bf16_t* __restrict__ aggh_r,
    const bf16_t* __restrict__ Wm2, const float* __restrict__ bm2,
    const bf16_t* __restrict__ Wr2, const float* __restrict__ br2,
    const int* __restrict__ start_to, const int* __restrict__ start_from,
    bf16_t* __restrict__ agg)
{
  constexpr int HS = 264;
  __shared__ bf16_t Af[64*HS];
  __shared__ bf16_t Ar[64*HS];
  const int tid = threadIdx.x;
  const int rb = blockIdx.x*64;
  #pragma unroll
  for (int it=0; it<8; ++it){
    int c = tid + it*256;        // 2048 chunks of 8 bf16
    int row = c >> 5;
    int co  = (c & 31) * 8;
    *(bf16x8*)&Af[row*HS+co] = *(const bf16x8*)&aggh_f[(size_t)(rb+row)*HH + co];
    *(bf16x8*)&Ar[row*HS+co] = *(const bf16x8*)&aggh_r[(size_t)(rb+row)*HH + co];
  }
  __syncthreads();

  const int lane = tid & 63, wave = tid >> 6, lr = lane & 15, lk = lane >> 4;
  f32x4 acc[16];
  #pragma unroll
  for (int nt=0;nt<16;nt++) acc[nt] = (f32x4){0.f,0.f,0.f,0.f};
  #pragma unroll
  for (int kc=0;kc<8;kc++){
    bf16x8 a = *(const bf16x8*)&Af[(wave*16 + lr)*HS + kc*32 + lk*8];
    #pragma unroll
    for (int nt=0;nt<16;nt++){
      bf16x8 b = *(const bf16x8*)&Wm2[(size_t)(nt*16 + lr)*HH + kc*32 + lk*8];
      acc[nt] = MFMA16(a,b,acc[nt]);
    }
  }
  #pragma unroll
  for (int kc=0;kc<8;kc++){
    bf16x8 a = *(const bf16x8*)&Ar[(wave*16 + lr)*HS + kc*32 + lk*8];
    #pragma unroll
    for (int nt=0;nt<16;nt++){
      bf16x8 b = *(const bf16x8*)&Wr2[(size_t)(nt*16 + lr)*HH + kc*32 + lk*8];
      acc[nt] = MFMA16(a,b,acc[nt]);
    }
  }
  #pragma unroll
  for (int nt=0;nt<16;nt++){
    const int col = nt*16 + lr;
    const float bm = bm2[col], br = br2[col];
    #pragma unroll
    for (int r=0;r<4;r++){
      const int row = rb + wave*16 + lk*4 + r;
      const float dt = (float)(start_to[row+1]   - start_to[row]);
      const float df = (float)(start_from[row+1] - start_from[row]);
      agg[(size_t)row*HH + col] = (bf16_t)(acc[nt][r] + dt*bm + df*br);
    }
  }
}

// ---------------- cross-graph attention (flash style) ----------------
__global__ __launch_bounds__(256,2) void attn_kernel(
    const float* __restrict__ ns, float* __restrict__ attn)
{
  constexpr int KS = 136;
  constexpr int VS = 40;
  __shared__ bf16_t Ks[32*KS];
  __shared__ bf16_t Vt[128*VS];
  __shared__ bf16_t Ps[64*VS];
  const int tid = threadIdx.x;
  const int lane = tid & 63, wave = tid >> 6, lr = lane & 15, lk = lane >> 4;
  const int bx = blockIdx.x;
  const int qt = bx & 31, side = (bx>>5)&1, p = bx>>6;
  const size_t qbase  = (size_t)p*4096 + (size_t)side*2048 + (size_t)qt*64;
  const size_t kvbase = (size_t)p*4096 + (size_t)(side^1)*2048;

  bf16x8 qf[4];
  {
    const float* qrow = ns + (qbase + wave*16 + lr)*DD;
    #pragma unroll
    for (int kc=0;kc<4;kc++){
      f32x4 v0 = *(const f32x4*)(qrow + kc*32 + lk*8);
      f32x4 v1 = *(const f32x4*)(qrow + kc*32 + lk*8 + 4);
      qf[kc] = cvt8(v0,v1);
    }
  }
  float m0[4], ls[4];
  #pragma unroll
  for (int r=0;r<4;r++){ m0[r] = -3.0e38f; ls[r] = 0.f; }
  f32x4 acco[8];
  #pragma unroll
  for (int nt=0;nt<8;nt++) acco[nt]=(f32x4){0.f,0.f,0.f,0.f};

  for (int kt=0; kt<64; ++kt){
    __syncthreads();
    {
      const int row = tid >> 3;
      const int c0  = (tid & 7)*16;
      const float* src = ns + (kvbase + (size_t)kt*32 + row)*DD + c0;
      #pragma unroll
      for (int j=0;j<4;j++){
        f32x4 v = *(const f32x4*)(src + j*4);
        bf16x4 o; o[0]=(bf16_t)v[0]; o[1]=(bf16_t)v[1]; o[2]=(bf16_t)v[2]; o[3]=(bf16_t)v[3];
        *(bf16x4*)&Ks[row*KS + c0 + j*4] = o;
        Vt[(c0+j*4+0)*VS + row] = o[0];
        Vt[(c0+j*4+1)*VS + row] = o[1];
        Vt[(c0+j*4+2)*VS + row] = o[2];
        Vt[(c0+j*4+3)*VS + row] = o[3];
      }
    }
    __syncthreads();

    f32x4 s0 = (f32x4){0.f,0.f,0.f,0.f}, s1 = (f32x4){0.f,0.f,0.f,0.f};
    #pragma unroll
    for (int kc=0;kc<4;kc++){
      bf16x8 b0 = *(const bf16x8*)&Ks[lr*KS       + kc*32 + lk*8];
      bf16x8 b1 = *(const bf16x8*)&Ks[(16+lr)*KS  + kc*32 + lk*8];
      s0 = MFMA16(qf[kc], b0, s0);
      s1 = MFMA16(qf[kc], b1, s1);
    }
    #pragma unroll
    for (int r=0;r<4;r++){
      float mr = fmaxf(s0[r], s1[r]);
      mr = fmaxf(mr, __shfl_xor(mr, 1));
      mr = fmaxf(mr, __shfl_xor(mr, 2));
      mr = fmaxf(mr, __shfl_xor(mr, 4));
      mr = fmaxf(mr, __shfl_xor(mr, 8));
      const float mnew  = fmaxf(m0[r], mr);
      const float scale = __expf(m0[r] - mnew);
      m0[r] = mnew;
      const float p0 = __expf(s0[r] - mnew);
      const float p1 = __expf(s1[r] - mnew);
      float rs = p0 + p1;
      rs += __shfl_xor(rs, 1);
      rs += __shfl_xor(rs, 2);
      rs += __shfl_xor(rs, 4);
      rs += __shfl_xor(rs, 8);
      ls[r] = ls[r]*scale + rs;
      #pragma unroll
      for (int nt=0;nt<8;nt++) acco[nt][r] *= scale;
      Ps[(wave*16 + lk*4 + r)*VS + lr]      = (bf16_t)p0;
      Ps[(wave*16 + lk*4 + r)*VS + 16 + lr] = (bf16_t)p1;
    }
    asm volatile("s_waitcnt lgkmcnt(0)" ::: "memory");
    __builtin_amdgcn_sched_barrier(0);
    bf16x8 pa = *(const bf16x8*)&Ps[(wave*16 + lr)*VS + lk*8];
    #pragma unroll
    for (int nt=0;nt<8;nt++){
      bf16x8 vb = *(const bf16x8*)&Vt[(nt*16+lr)*VS + lk*8];
      acco[nt] = MFMA16(pa, vb, acco[nt]);
    }
  }
  float inv[4];
  #pragma unroll
  for (int r=0;r<4;r++) inv[r] = 1.f/ls[r];
  #pragma unroll
  for (int nt=0;nt<8;nt++){
    const int col = nt*16 + lr;
    #pragma unroll
    for (int r=0;r<4;r++){
      const size_t row = qbase + wave*16 + lk*4 + r;
      attn[row*DD + col] = ns[row*DD + col] - acco[nt][r]*inv[r];
    }
  }
}

// ---------------- node MLP + residual ----------------
__global__ __launch_bounds__(256,4) void node_mlp_kernel(
    const bf16_t* __restrict__ aggb, const float* __restrict__ attn,
    const float* __restrict__ ns,
    const bf16_t* __restrict__ Wn1b, const float* __restrict__ bn1,
    const bf16_t* __restrict__ Wn2b, const float* __restrict__ bn2,
    float* __restrict__ out)
{
  constexpr int HS = 264;
  __shared__ bf16_t Hs[64*HS];
  const int tid = threadIdx.x;
  const int lane = tid & 63, wave = tid >> 6, lr = lane & 15, lk = lane >> 4;
  const int rb = blockIdx.x*64;
  const int row = rb + wave*16 + lr;

  f32x4 acc[16];
  #pragma unroll
  for (int nt=0;nt<16;nt++) acc[nt] = (f32x4){0.f,0.f,0.f,0.f};
  // K-chunks 0..7: agg (bf16 direct)
  #pragma unroll
  for (int kc=0;kc<8;kc++){
    bf16x8 a = *(const bf16x8*)&aggb[(size_t)row*HH + kc*32 + lk*8];
    #pragma unroll
    for (int nt=0;nt<16;nt++){
      bf16x8 b = *(const bf16x8*)&Wn1b[(size_t)(nt*16 + lr)*512 + kc*32 + lk*8];
      acc[nt] = MFMA16(a,b,acc[nt]);
    }
  }
  // K-chunks 8..15: attn (f32), ns (f32)
  #pragma unroll
  for (int kc=8;kc<16;kc++){
    const float* s; int col;
    if (kc <12) { s = attn + (size_t)row*DD; col = kc*32 + lk*8 - 256; }
    else        { s = ns   + (size_t)row*DD; col = kc*32 + lk*8 - 384; }
    f32x4 v0 = *(const f32x4*)(s + col);
    f32x4 v1 = *(const f32x4*)(s + col + 4);
    bf16x8 a = cvt8(v0,v1);
    #pragma unroll
    for (int nt=0;nt<16;nt++){
      bf16x8 b = *(const bf16x8*)&Wn1b[(size_t)(nt*16 + lr)*512 + kc*32 + lk*8];
      acc[nt] = MFMA16(a,b,acc[nt]);
    }
  }
  #pragma unroll
  for (int nt=0;nt<16;nt++){
    float bias = bn1[nt*16 + lr];
    #pragma unroll
    for (int r=0;r<4;r++){
      float v = acc[nt][r] + bias;
      v = v > 0.f ? v : 0.f;
      Hs[(wave*16 + lk*4 + r)*HS + nt*16 + lr] = (bf16_t)v;
    }
  }
  asm volatile("s_waitcnt lgkmcnt(0)" ::: "memory");
  __builtin_amdgcn_sched_barrier(0);

  f32x4 acc2[8];
  #pragma unroll
  for (int nt=0;nt<8;nt++) acc2[nt] = (f32x4){0.f,0.f,0.f,0.f};
  #pragma unroll
  for (int kc=0;kc<8;kc++){
    bf16x8 a = *(const bf16x8*)&Hs[(wave*16 + lr)*HS + kc*32 + lk*8];
    #pragma unroll
    for (int nt=0;nt<8;nt++){
      bf16x8 b = *(const bf16x8*)&Wn2b[(size_t)(nt*16 + lr)*HH + kc*32 + lk*8];
      acc2[nt] = MFMA16(a,b,acc2[nt]);
    }
  }
  const int r0 = rb + wave*16 + lk*4;
  #pragma unroll
  for (int nt=0;nt<8;nt++){
    const int col = nt*16 + lr;
    const float bias = bn2[col];
    #pragma unroll
    for (int r=0;r<4;r++){
      const size_t rr = (size_t)(r0 + r);
      out[rr*DD + col] = acc2[nt][r] + bias + ns[rr*DD + col];
    }
  }
}

extern "C" void kernel_launch(void* const* d_in, const int* in_sizes, int n_in,
                              void* d_out, int out_size, void* d_ws, size_t ws_size,
                              hipStream_t stream) {
  const float* ns  = (const float*)d_in[0];
  const float* ef  = (const float*)d_in[1];
  const int* from_idx = (const int*)d_in[2];
  const int* to_idx   = (const int*)d_in[3];
  const float* Wm1 = (const float*)d_in[6];  const float* bm1 = (const float*)d_in[7];
  const float* Wm2 = (const float*)d_in[8];  const float* bm2 = (const float*)d_in[9];
  const float* Wr1 = (const float*)d_in[10]; const float* br1 = (const float*)d_in[11];
  const float* Wr2 = (const float*)d_in[12]; const float* br2 = (const float*)d_in[13];
  const float* Wn1 = (const float*)d_in[14]; const float* bn1 = (const float*)d_in[15];
  const float* Wn2 = (const float*)d_in[16]; const float* bn2 = (const float*)d_in[17];

  char* ws = (char*)d_ws;
  bf16_t* msg    = (bf16_t*)(ws);                      // 262144*256*2 = 134,217,728
  bf16_t* aggh_f = (bf16_t*)(ws + 134217728);          // 16,777,216
  bf16_t* aggh_r = (bf16_t*)(ws + 150994944);          // 16,777,216
  bf16_t* aggb   = (bf16_t*)(ws + 167772160);          // 16,777,216
  float*  attn   = (float*) (ws + 184549376);          // 16,777,216
  bf16_t* wm1b = (bf16_t*)(ws + 201326592);            // 163,840
  bf16_t* wm2b = (bf16_t*)(ws + 201490432);            // 131,072
  bf16_t* wr1b = (bf16_t*)(ws + 201621504);            // 163,840
  bf16_t* wr2b = (bf16_t*)(ws + 201785344);            // 131,072
  bf16_t* wn1b = (bf16_t*)(ws + 201916416);            // 262,144
  bf16_t* wn2b = (bf16_t*)(ws + 202178560);            // 65,536
  int* cur_to     = (int*)(ws + 202244096);            // 131,072
  int* cur_from   = (int*)(ws + 202375168);            // 131,072
  int* start_to   = (int*)(ws + 202506240);            // 131,080
  int* start_from = (int*)(ws + 202637320);            // 131,080
  int* eid_to     = (int*)(ws + 202768400);            // 1,048,576
  int* eid_from   = (int*)(ws + 203816976);            // 1,048,576

  // zero histograms (cur_to, cur_from are contiguous)
  hipMemsetAsync(cur_to, 0, 2*NNODES*sizeof(int), stream);

  cvt_kernel<<<80, 256, 0, stream>>>(Wm1, wm1b, 256*320);
  cvt_kernel<<<64, 256, 0, stream>>>(Wm2, wm2b, 256*256);
  cvt_kernel<<<80, 256, 0, stream>>>(Wr1, wr1b, 256*320);
  cvt_kernel<<<64, 256, 0, stream>>>(Wr2, wr2b, 256*256);
  cvt_kernel<<<128,256, 0, stream>>>(Wn1, wn1b, 256*512);
  cvt_kernel<<<32, 256, 0, stream>>>(Wn2, wn2b, 128*256);

  // CSR build
  hist_kernel<<<NEDGES/256, 256, 0, stream>>>(to_idx, from_idx, cur_to, cur_from);
  scan_kernel<<<1, 1024, 0, stream>>>(cur_to, start_to);
  scan_kernel<<<1, 1024, 0, stream>>>(cur_from, start_from);
  place_kernel<<<NEDGES/256, 256, 0, stream>>>(to_idx, from_idx, cur_to, cur_from, eid_to, eid_from);

  // attention (independent of edge path)
  attn_kernel<<<512, 256, 0, stream>>>(ns, attn);

  // forward direction: h_fwd -> aggregate by to_idx
  edge_h_kernel<<<NEDGES/64, 256, 0, stream>>>(ns, ef, from_idx, to_idx, wm1b, bm1, msg, 0);
  agg_h_kernel<<<NNODES/4, 256, 0, stream>>>(msg, start_to, eid_to, aggh_f);

  // reverse direction: h_rev -> aggregate by from_idx (reuses msg buffer)
  edge_h_kernel<<<NEDGES/64, 256, 0, stream>>>(ns, ef, from_idx, to_idx, wr1b, br1, msg, 1);
  agg_h_kernel<<<NNODES/4, 256, 0, stream>>>(msg, start_from, eid_from, aggh_r);

  // agg = aggh_f @ Wm2^T + deg_to*bm2 + aggh_r @ Wr2^T + deg_from*br2
  agg_gemm_kernel<<<NNODES/64, 256, 0, stream>>>(aggh_f, aggh_r, wm2b, bm2, wr2b, br2,
                                                 start_to, start_from, aggb);

  node_mlp_kernel<<<NNODES/64, 256, 0, stream>>>(aggb, attn, ns,
      wn1b, bn1, wn2b, bn2, (float*)d_out);
}

// Round 3
// 833.125 us; speedup vs baseline: 1.8363x; 1.5226x over previous
//
#include <hip/hip_runtime.h>

typedef __bf16 bf16_t;
typedef __bf16 bf16x8 __attribute__((ext_vector_type(8)));
typedef __bf16 bf16x4 __attribute__((ext_vector_type(4)));
typedef float  f32x4  __attribute__((ext_vector_type(4)));

#define MFMA16(a,b,c) __builtin_amdgcn_mfma_f32_16x16x32_bf16((a),(b),(c),0,0,0)

constexpr int NNODES = 32768;
constexpr int NEDGES = 262144;
constexpr int DD = 128;
constexpr int HH = 256;

__device__ __forceinline__ bf16x8 cvt8(f32x4 a, f32x4 b){
  bf16x8 r;
  r[0]=(bf16_t)a[0]; r[1]=(bf16_t)a[1]; r[2]=(bf16_t)a[2]; r[3]=(bf16_t)a[3];
  r[4]=(bf16_t)b[0]; r[5]=(bf16_t)b[1]; r[6]=(bf16_t)b[2]; r[7]=(bf16_t)b[3];
  return r;
}

__global__ void cvt_kernel(const float* __restrict__ in, bf16_t* __restrict__ out, int n){
  int i = (blockIdx.x*256 + threadIdx.x)*4;
  if (i < n){
    f32x4 v = *(const f32x4*)(in + i);
    bf16x4 o; o[0]=(bf16_t)v[0]; o[1]=(bf16_t)v[1]; o[2]=(bf16_t)v[2]; o[3]=(bf16_t)v[3];
    *(bf16x4*)(out + i) = o;
  }
}

// wpb[1024][128]: rows 0..255 = Wm1[:,0:128], 256..511 = Wm1[:,128:256],
//                 512..767 = Wr1[:,0:128], 768..1023 = Wr1[:,128:256]
__global__ void cvt_wp_kernel(const float* __restrict__ Wm1, const float* __restrict__ Wr1,
                              bf16_t* __restrict__ wp){
  int idx = (blockIdx.x*256 + threadIdx.x)*4;   // < 131072
  int n = idx >> 7, k = idx & 127;
  const float* W = (n < 512) ? Wm1 : Wr1;
  int row = n & 255;
  int colbase = ((n >> 8) & 1) * 128;
  f32x4 v = *(const f32x4*)(W + (size_t)row*320 + colbase + k);
  bf16x4 o; o[0]=(bf16_t)v[0]; o[1]=(bf16_t)v[1]; o[2]=(bf16_t)v[2]; o[3]=(bf16_t)v[3];
  *(bf16x4*)(wp + idx) = o;
}

// wcb[512][64]: rows 0..255 = Wm1[:,256:320], 256..511 = Wr1[:,256:320]
__global__ void cvt_wc_kernel(const float* __restrict__ Wm1, const float* __restrict__ Wr1,
                              bf16_t* __restrict__ wc){
  int idx = (blockIdx.x*256 + threadIdx.x)*4;   // < 32768
  int n = idx >> 6, k = idx & 63;
  const float* W = (n < 256) ? Wm1 : Wr1;
  int row = n & 255;
  f32x4 v = *(const f32x4*)(W + (size_t)row*320 + 256 + k);
  bf16x4 o; o[0]=(bf16_t)v[0]; o[1]=(bf16_t)v[1]; o[2]=(bf16_t)v[2]; o[3]=(bf16_t)v[3];
  *(bf16x4*)(wc + idx) = o;
}

// ---------------- CSR build ----------------
__global__ void hist_kernel(const int* __restrict__ to_idx, const int* __restrict__ from_idx,
                            int* __restrict__ cnt_to, int* __restrict__ cnt_from){
  int e = blockIdx.x*256 + threadIdx.x;
  if (e < NEDGES){
    atomicAdd(&cnt_to[to_idx[e]], 1);
    atomicAdd(&cnt_from[from_idx[e]], 1);
  }
}

__global__ void scan_kernel(int* __restrict__ cnt, int* __restrict__ start){
  __shared__ int sums[1024];
  const int t = threadIdx.x;
  int local[32]; int s = 0;
  #pragma unroll
  for (int j=0;j<32;j++){ local[j] = cnt[t*32+j]; s += local[j]; }
  sums[t] = s; __syncthreads();
  #pragma unroll
  for (int d=1; d<1024; d<<=1){
    int v = (t>=d) ? sums[t-d] : 0;
    __syncthreads();
    sums[t] += v;
    __syncthreads();
  }
  int off = sums[t] - s;
  #pragma unroll
  for (int j=0;j<32;j++){
    start[t*32+j] = off;
    cnt[t*32+j]   = off;
    off += local[j];
  }
  if (t == 1023) start[32768] = sums[1023];
}

__global__ void place_kernel(const int* __restrict__ to_idx, const int* __restrict__ from_idx,
                             int* __restrict__ cur_to, int* __restrict__ cur_from,
                             int* __restrict__ eid_to, int* __restrict__ eid_from){
  int e = blockIdx.x*256 + threadIdx.x;
  if (e < NEDGES){
    int p = atomicAdd(&cur_to[to_idx[e]], 1);
    eid_to[p] = e;
    int q = atomicAdd(&cur_from[from_idx[e]], 1);
    eid_from[q] = e;
  }
}

// ---------------- node projections: P = ns @ Wblock^T (K=128) ----------------
// blockIdx.y: 0 -> P1 (first 256 rows of Wp), 1 -> P2 (next 256 rows)
__global__ __launch_bounds__(256,3) void proj_kernel(
    const float* __restrict__ ns, const bf16_t* __restrict__ Wp,
    bf16_t* __restrict__ P1, bf16_t* __restrict__ P2)
{
  constexpr int XS = 136;
  constexpr int CS = 264;
  __shared__ bf16_t Xs[64*XS];
  __shared__ bf16_t Cs[64*CS];
  const int tid = threadIdx.x;
  const int rb = blockIdx.x*64;
  const int cb = blockIdx.y;
  #pragma unroll
  for (int it=0; it<8; ++it){
    int c = tid + it*256;            // 2048 chunks of 4 f32
    int row = c >> 5, co = (c & 31)*4;
    f32x4 v = *(const f32x4*)(ns + (size_t)(rb+row)*DD + co);
    bf16x4 o; o[0]=(bf16_t)v[0]; o[1]=(bf16_t)v[1]; o[2]=(bf16_t)v[2]; o[3]=(bf16_t)v[3];
    *(bf16x4*)&Xs[row*XS + co] = o;
  }
  __syncthreads();
  const int lane = tid & 63, wave = tid >> 6, lr = lane & 15, lk = lane >> 4;
  const bf16_t* Wb = Wp + (size_t)cb*256*128;
  f32x4 acc[16];
  #pragma unroll
  for (int nt=0;nt<16;nt++) acc[nt] = (f32x4){0.f,0.f,0.f,0.f};
  #pragma unroll
  for (int kc=0;kc<4;kc++){
    bf16x8 a = *(const bf16x8*)&Xs[(wave*16 + lr)*XS + kc*32 + lk*8];
    #pragma unroll
    for (int nt=0;nt<16;nt++){
      bf16x8 b = *(const bf16x8*)&Wb[(size_t)(nt*16 + lr)*128 + kc*32 + lk*8];
      acc[nt] = MFMA16(a,b,acc[nt]);
    }
  }
  #pragma unroll
  for (int nt=0;nt<16;nt++)
    #pragma unroll
    for (int r=0;r<4;r++)
      Cs[(wave*16 + lk*4 + r)*CS + nt*16 + lr] = (bf16_t)acc[nt][r];
  __syncthreads();
  bf16_t* P = cb ? P2 : P1;
  #pragma unroll
  for (int it=0; it<8; ++it){
    int c = tid + it*256;            // 2048 chunks of 8 bf16
    int row = c >> 5, co = (c & 31)*8;
    *(bf16x8*)&P[(size_t)(rb+row)*HH + co] = *(const bf16x8*)&Cs[row*CS + co];
  }
}

// ---------------- edge projection: Ec = ef @ Wc^T (K=64, coalesced) ----------------
__global__ __launch_bounds__(256,3) void ec_kernel(
    const float* __restrict__ ef, const bf16_t* __restrict__ Wc,
    bf16_t* __restrict__ Ec)
{
  constexpr int XS = 72;
  constexpr int CS = 264;
  __shared__ bf16_t Xs[64*XS];
  __shared__ bf16_t Cs[64*CS];
  const int tid = threadIdx.x;
  const int eb = blockIdx.x*64;
  #pragma unroll
  for (int it=0; it<4; ++it){
    int c = tid + it*256;            // 1024 chunks of 4 f32
    int row = c >> 4, co = (c & 15)*4;
    f32x4 v = *(const f32x4*)(ef + (size_t)(eb+row)*64 + co);
    bf16x4 o; o[0]=(bf16_t)v[0]; o[1]=(bf16_t)v[1]; o[2]=(bf16_t)v[2]; o[3]=(bf16_t)v[3];
    *(bf16x4*)&Xs[row*XS + co] = o;
  }
  __syncthreads();
  const int lane = tid & 63, wave = tid >> 6, lr = lane & 15, lk = lane >> 4;
  f32x4 acc[16];
  #pragma unroll
  for (int nt=0;nt<16;nt++) acc[nt] = (f32x4){0.f,0.f,0.f,0.f};
  #pragma unroll
  for (int kc=0;kc<2;kc++){
    bf16x8 a = *(const bf16x8*)&Xs[(wave*16 + lr)*XS + kc*32 + lk*8];
    #pragma unroll
    for (int nt=0;nt<16;nt++){
      bf16x8 b = *(const bf16x8*)&Wc[(size_t)(nt*16 + lr)*64 + kc*32 + lk*8];
      acc[nt] = MFMA16(a,b,acc[nt]);
    }
  }
  #pragma unroll
  for (int nt=0;nt<16;nt++)
    #pragma unroll
    for (int r=0;r<4;r++)
      Cs[(wave*16 + lk*4 + r)*CS + nt*16 + lr] = (bf16_t)acc[nt][r];
  __syncthreads();
  #pragma unroll
  for (int it=0; it<8; ++it){
    int c = tid + it*256;
    int row = c >> 5, co = (c & 31)*8;
    *(bf16x8*)&Ec[(size_t)(eb+row)*HH + co] = *(const bf16x8*)&Cs[row*CS + co];
  }
}

// ---------------- fused combine + aggregate (pure gather-reduce) ----------------
// aggh[v] = sum_{i in [start[v],start[v+1])} relu(Ec[eid[i]] + P1[oth[eid[i]]] + P2[v] + b1)
__global__ __launch_bounds__(256) void gather_agg_kernel(
    const bf16_t* __restrict__ Ec, const bf16_t* __restrict__ P1,
    const bf16_t* __restrict__ P2, const float* __restrict__ b1,
    const int* __restrict__ start, const int* __restrict__ eid,
    const int* __restrict__ oth, bf16_t* __restrict__ aggh)
{
  const int wave = threadIdx.x >> 6;
  const int lane = threadIdx.x & 63;
  const int v = blockIdx.x*4 + wave;
  const int c0 = lane*4;
  float base[4];
  {
    bf16x4 p2 = *(const bf16x4*)&P2[(size_t)v*HH + c0];
    f32x4  bb = *(const f32x4*)(b1 + c0);
    #pragma unroll
    for (int j=0;j<4;j++) base[j] = (float)p2[j] + bb[j];
  }
  float acc[4] = {0.f,0.f,0.f,0.f};
  const int s = start[v], e_end = start[v+1];
  for (int i=s; i<e_end; ++i){
    const int e = eid[i];
    const int o = oth[e];
    bf16x4 ec = *(const bf16x4*)&Ec[(size_t)e*HH + c0];
    bf16x4 p1 = *(const bf16x4*)&P1[(size_t)o*HH + c0];
    #pragma unroll
    for (int j=0;j<4;j++){
      float x = base[j] + (float)ec[j] + (float)p1[j];
      acc[j] += fmaxf(x, 0.f);
    }
  }
  bf16x4 out;
  #pragma unroll
  for (int j=0;j<4;j++) out[j] = (bf16_t)acc[j];
  *(bf16x4*)&aggh[(size_t)v*HH + c0] = out;
}

// ---------------- agg = aggh_f @ Wm2^T + deg_to*bm2 + aggh_r @ Wr2^T + deg_from*br2 ----------------
__global__ __launch_bounds__(256,2) void agg_gemm_kernel(
    const bf16_t* __restrict__ aggh_f, const bf16_t* __restrict__ aggh_r,
    const bf16_t* __restrict__ Wm2, const float* __restrict__ bm2,
    const bf16_t* __restrict__ Wr2, const float* __restrict__ br2,
    const int* __restrict__ start_to, const int* __restrict__ start_from,
    bf16_t* __restrict__ agg)
{
  constexpr int HS = 264;
  __shared__ bf16_t Af[64*HS];
  __shared__ bf16_t Ar[64*HS];
  const int tid = threadIdx.x;
  const int rb = blockIdx.x*64;
  #pragma unroll
  for (int it=0; it<8; ++it){
    int c = tid + it*256;
    int row = c >> 5;
    int co  = (c & 31) * 8;
    *(bf16x8*)&Af[row*HS+co] = *(const bf16x8*)&aggh_f[(size_t)(rb+row)*HH + co];
    *(bf16x8*)&Ar[row*HS+co] = *(const bf16x8*)&aggh_r[(size_t)(rb+row)*HH + co];
  }
  __syncthreads();

  const int lane = tid & 63, wave = tid >> 6, lr = lane & 15, lk = lane >> 4;
  f32x4 acc[16];
  #pragma unroll
  for (int nt=0;nt<16;nt++) acc[nt] = (f32x4){0.f,0.f,0.f,0.f};
  #pragma unroll
  for (int kc=0;kc<8;kc++){
    bf16x8 a = *(const bf16x8*)&Af[(wave*16 + lr)*HS + kc*32 + lk*8];
    #pragma unroll
    for (int nt=0;nt<16;nt++){
      bf16x8 b = *(const bf16x8*)&Wm2[(size_t)(nt*16 + lr)*HH + kc*32 + lk*8];
      acc[nt] = MFMA16(a,b,acc[nt]);
    }
  }
  #pragma unroll
  for (int kc=0;kc<8;kc++){
    bf16x8 a = *(const bf16x8*)&Ar[(wave*16 + lr)*HS + kc*32 + lk*8];
    #pragma unroll
    for (int nt=0;nt<16;nt++){
      bf16x8 b = *(const bf16x8*)&Wr2[(size_t)(nt*16 + lr)*HH + kc*32 + lk*8];
      acc[nt] = MFMA16(a,b,acc[nt]);
    }
  }
  #pragma unroll
  for (int nt=0;nt<16;nt++){
    const int col = nt*16 + lr;
    const float bm = bm2[col], br = br2[col];
    #pragma unroll
    for (int r=0;r<4;r++){
      const int row = rb + wave*16 + lk*4 + r;
      const float dt = (float)(start_to[row+1]   - start_to[row]);
      const float df = (float)(start_from[row+1] - start_from[row]);
      agg[(size_t)row*HH + col] = (bf16_t)(acc[nt][r] + dt*bm + df*br);
    }
  }
}

// ---------------- cross-graph attention (flash style) ----------------
__global__ __launch_bounds__(256,2) void attn_kernel(
    const float* __restrict__ ns, float* __restrict__ attn)
{
  constexpr int KS = 136;
  constexpr int VS = 40;
  __shared__ bf16_t Ks[32*KS];
  __shared__ bf16_t Vt[128*VS];
  __shared__ bf16_t Ps[64*VS];
  const int tid = threadIdx.x;
  const int lane = tid & 63, wave = tid >> 6, lr = lane & 15, lk = lane >> 4;
  const int bx = blockIdx.x;
  const int qt = bx & 31, side = (bx>>5)&1, p = bx>>6;
  const size_t qbase  = (size_t)p*4096 + (size_t)side*2048 + (size_t)qt*64;
  const size_t kvbase = (size_t)p*4096 + (size_t)(side^1)*2048;

  bf16x8 qf[4];
  {
    const float* qrow = ns + (qbase + wave*16 + lr)*DD;
    #pragma unroll
    for (int kc=0;kc<4;kc++){
      f32x4 v0 = *(const f32x4*)(qrow + kc*32 + lk*8);
      f32x4 v1 = *(const f32x4*)(qrow + kc*32 + lk*8 + 4);
      qf[kc] = cvt8(v0,v1);
    }
  }
  float m0[4], ls[4];
  #pragma unroll
  for (int r=0;r<4;r++){ m0[r] = -3.0e38f; ls[r] = 0.f; }
  f32x4 acco[8];
  #pragma unroll
  for (int nt=0;nt<8;nt++) acco[nt]=(f32x4){0.f,0.f,0.f,0.f};

  for (int kt=0; kt<64; ++kt){
    __syncthreads();
    {
      const int row = tid >> 3;
      const int c0  = (tid & 7)*16;
      const float* src = ns + (kvbase + (size_t)kt*32 + row)*DD + c0;
      #pragma unroll
      for (int j=0;j<4;j++){
        f32x4 v = *(const f32x4*)(src + j*4);
        bf16x4 o; o[0]=(bf16_t)v[0]; o[1]=(bf16_t)v[1]; o[2]=(bf16_t)v[2]; o[3]=(bf16_t)v[3];
        *(bf16x4*)&Ks[row*KS + c0 + j*4] = o;
        Vt[(c0+j*4+0)*VS + row] = o[0];
        Vt[(c0+j*4+1)*VS + row] = o[1];
        Vt[(c0+j*4+2)*VS + row] = o[2];
        Vt[(c0+j*4+3)*VS + row] = o[3];
      }
    }
    __syncthreads();

    f32x4 s0 = (f32x4){0.f,0.f,0.f,0.f}, s1 = (f32x4){0.f,0.f,0.f,0.f};
    #pragma unroll
    for (int kc=0;kc<4;kc++){
      bf16x8 b0 = *(const bf16x8*)&Ks[lr*KS       + kc*32 + lk*8];
      bf16x8 b1 = *(const bf16x8*)&Ks[(16+lr)*KS  + kc*32 + lk*8];
      s0 = MFMA16(qf[kc], b0, s0);
      s1 = MFMA16(qf[kc], b1, s1);
    }
    #pragma unroll
    for (int r=0;r<4;r++){
      float mr = fmaxf(s0[r], s1[r]);
      mr = fmaxf(mr, __shfl_xor(mr, 1));
      mr = fmaxf(mr, __shfl_xor(mr, 2));
      mr = fmaxf(mr, __shfl_xor(mr, 4));
      mr = fmaxf(mr, __shfl_xor(mr, 8));
      const float mnew  = fmaxf(m0[r], mr);
      const float scale = __expf(m0[r] - mnew);
      m0[r] = mnew;
      const float p0 = __expf(s0[r] - mnew);
      const float p1 = __expf(s1[r] - mnew);
      float rs = p0 + p1;
      rs += __shfl_xor(rs, 1);
      rs += __shfl_xor(rs, 2);
      rs += __shfl_xor(rs, 4);
      rs += __shfl_xor(rs, 8);
      ls[r] = ls[r]*scale + rs;
      #pragma unroll
      for (int nt=0;nt<8;nt++) acco[nt][r] *= scale;
      Ps[(wave*16 + lk*4 + r)*VS + lr]      = (bf16_t)p0;
      Ps[(wave*16 + lk*4 + r)*VS + 16 + lr] = (bf16_t)p1;
    }
    asm volatile("s_waitcnt lgkmcnt(0)" ::: "memory");
    __builtin_amdgcn_sched_barrier(0);
    bf16x8 pa = *(const bf16x8*)&Ps[(wave*16 + lr)*VS + lk*8];
    #pragma unroll
    for (int nt=0;nt<8;nt++){
      bf16x8 vb = *(const bf16x8*)&Vt[(nt*16+lr)*VS + lk*8];
      acco[nt] = MFMA16(pa, vb, acco[nt]);
    }
  }
  float inv[4];
  #pragma unroll
  for (int r=0;r<4;r++) inv[r] = 1.f/ls[r];
  #pragma unroll
  for (int nt=0;nt<8;nt++){
    const int col = nt*16 + lr;
    #pragma unroll
    for (int r=0;r<4;r++){
      const size_t row = qbase + wave*16 + lk*4 + r;
      attn[row*DD + col] = ns[row*DD + col] - acco[nt][r]*inv[r];
    }
  }
}

// ---------------- node MLP + residual ----------------
__global__ __launch_bounds__(256,4) void node_mlp_kernel(
    const bf16_t* __restrict__ aggb, const float* __restrict__ attn,
    const float* __restrict__ ns,
    const bf16_t* __restrict__ Wn1b, const float* __restrict__ bn1,
    const bf16_t* __restrict__ Wn2b, const float* __restrict__ bn2,
    float* __restrict__ out)
{
  constexpr int HS = 264;
  __shared__ bf16_t Hs[64*HS];
  const int tid = threadIdx.x;
  const int lane = tid & 63, wave = tid >> 6, lr = lane & 15, lk = lane >> 4;
  const int rb = blockIdx.x*64;
  const int row = rb + wave*16 + lr;

  f32x4 acc[16];
  #pragma unroll
  for (int nt=0;nt<16;nt++) acc[nt] = (f32x4){0.f,0.f,0.f,0.f};
  #pragma unroll
  for (int kc=0;kc<8;kc++){
    bf16x8 a = *(const bf16x8*)&aggb[(size_t)row*HH + kc*32 + lk*8];
    #pragma unroll
    for (int nt=0;nt<16;nt++){
      bf16x8 b = *(const bf16x8*)&Wn1b[(size_t)(nt*16 + lr)*512 + kc*32 + lk*8];
      acc[nt] = MFMA16(a,b,acc[nt]);
    }
  }
  #pragma unroll
  for (int kc=8;kc<16;kc++){
    const float* s; int col;
    if (kc <12) { s = attn + (size_t)row*DD; col = kc*32 + lk*8 - 256; }
    else        { s = ns   + (size_t)row*DD; col = kc*32 + lk*8 - 384; }
    f32x4 v0 = *(const f32x4*)(s + col);
    f32x4 v1 = *(const f32x4*)(s + col + 4);
    bf16x8 a = cvt8(v0,v1);
    #pragma unroll
    for (int nt=0;nt<16;nt++){
      bf16x8 b = *(const bf16x8*)&Wn1b[(size_t)(nt*16 + lr)*512 + kc*32 + lk*8];
      acc[nt] = MFMA16(a,b,acc[nt]);
    }
  }
  #pragma unroll
  for (int nt=0;nt<16;nt++){
    float bias = bn1[nt*16 + lr];
    #pragma unroll
    for (int r=0;r<4;r++){
      float v = acc[nt][r] + bias;
      v = v > 0.f ? v : 0.f;
      Hs[(wave*16 + lk*4 + r)*HS + nt*16 + lr] = (bf16_t)v;
    }
  }
  asm volatile("s_waitcnt lgkmcnt(0)" ::: "memory");
  __builtin_amdgcn_sched_barrier(0);

  f32x4 acc2[8];
  #pragma unroll
  for (int nt=0;nt<8;nt++) acc2[nt] = (f32x4){0.f,0.f,0.f,0.f};
  #pragma unroll
  for (int kc=0;kc<8;kc++){
    bf16x8 a = *(const bf16x8*)&Hs[(wave*16 + lr)*HS + kc*32 + lk*8];
    #pragma unroll
    for (int nt=0;nt<8;nt++){
      bf16x8 b = *(const bf16x8*)&Wn2b[(size_t)(nt*16 + lr)*HH + kc*32 + lk*8];
      acc2[nt] = MFMA16(a,b,acc2[nt]);
    }
  }
  const int r0 = rb + wave*16 + lk*4;
  #pragma unroll
  for (int nt=0;nt<8;nt++){
    const int col = nt*16 + lr;
    const float bias = bn2[col];
    #pragma unroll
    for (int r=0;r<4;r++){
      const size_t rr = (size_t)(r0 + r);
      out[rr*DD + col] = acc2[nt][r] + bias + ns[rr*DD + col];
    }
  }
}

extern "C" void kernel_launch(void* const* d_in, const int* in_sizes, int n_in,
                              void* d_out, int out_size, void* d_ws, size_t ws_size,
                              hipStream_t stream) {
  const float* ns  = (const float*)d_in[0];
  const float* ef  = (const float*)d_in[1];
  const int* from_idx = (const int*)d_in[2];
  const int* to_idx   = (const int*)d_in[3];
  const float* Wm1 = (const float*)d_in[6];  const float* bm1 = (const float*)d_in[7];
  const float* Wm2 = (const float*)d_in[8];  const float* bm2 = (const float*)d_in[9];
  const float* Wr1 = (const float*)d_in[10]; const float* br1 = (const float*)d_in[11];
  const float* Wr2 = (const float*)d_in[12]; const float* br2 = (const float*)d_in[13];
  const float* Wn1 = (const float*)d_in[14]; const float* bn1 = (const float*)d_in[15];
  const float* Wn2 = (const float*)d_in[16]; const float* bn2 = (const float*)d_in[17];

  char* ws = (char*)d_ws;
  bf16_t* Ec     = (bf16_t*)(ws);                      // 262144*256*2 = 134,217,728
  bf16_t* P1t    = (bf16_t*)(ws + 134217728);          // 16,777,216
  bf16_t* P2t    = (bf16_t*)(ws + 150994944);          // 16,777,216
  bf16_t* aggh_f = (bf16_t*)(ws + 167772160);          // 16,777,216
  bf16_t* aggh_r = (bf16_t*)(ws + 184549376);          // 16,777,216
  bf16_t* wpb  = (bf16_t*)(ws + 201326592);            // 262,144
  bf16_t* wcb  = (bf16_t*)(ws + 201588736);            //  65,536
  bf16_t* wm2b = (bf16_t*)(ws + 201654272);            // 131,072
  bf16_t* wr2b = (bf16_t*)(ws + 201785344);            // 131,072
  bf16_t* wn1b = (bf16_t*)(ws + 201916416);            // 262,144
  bf16_t* wn2b = (bf16_t*)(ws + 202178560);            //  65,536
  int* cur_to     = (int*)(ws + 202244096);            // 131,072
  int* cur_from   = (int*)(ws + 202375168);            // 131,072
  int* start_to   = (int*)(ws + 202506240);            // 131,080
  int* start_from = (int*)(ws + 202637320);            // 131,080
  int* eid_to     = (int*)(ws + 202768400);            // 1,048,576
  int* eid_from   = (int*)(ws + 203816976);            // 1,048,576
  // after gather phases, Ec region is dead -> reuse for attn + aggb
  float*  attn = (float*) (ws);                        // 16,777,216
  bf16_t* aggb = (bf16_t*)(ws + 16777216);             // 16,777,216

  hipMemsetAsync(cur_to, 0, 2*NNODES*sizeof(int), stream);

  cvt_wp_kernel<<<128, 256, 0, stream>>>(Wm1, Wr1, wpb);
  cvt_wc_kernel<<<32, 256, 0, stream>>>(Wm1, Wr1, wcb);
  cvt_kernel<<<64, 256, 0, stream>>>(Wm2, wm2b, 256*256);
  cvt_kernel<<<64, 256, 0, stream>>>(Wr2, wr2b, 256*256);
  cvt_kernel<<<128,256, 0, stream>>>(Wn1, wn1b, 256*512);
  cvt_kernel<<<32, 256, 0, stream>>>(Wn2, wn2b, 128*256);

  hist_kernel<<<NEDGES/256, 256, 0, stream>>>(to_idx, from_idx, cur_to, cur_from);
  scan_kernel<<<1, 1024, 0, stream>>>(cur_to, start_to);
  scan_kernel<<<1, 1024, 0, stream>>>(cur_from, start_from);
  place_kernel<<<NEDGES/256, 256, 0, stream>>>(to_idx, from_idx, cur_to, cur_from, eid_to, eid_from);

  // ---- forward direction: h = relu(Pa[from] + Pb[to] + EcF[e] + bm1), agg at to ----
  proj_kernel<<<dim3(NNODES/64, 2), 256, 0, stream>>>(ns, wpb, P1t, P2t);
  ec_kernel<<<NEDGES/64, 256, 0, stream>>>(ef, wcb, Ec);
  gather_agg_kernel<<<NNODES/4, 256, 0, stream>>>(Ec, P1t, P2t, bm1,
      start_to, eid_to, from_idx, aggh_f);

  // ---- reverse direction: h = relu(PaR[to] + PbR[from] + EcR[e] + br1), agg at from ----
  proj_kernel<<<dim3(NNODES/64, 2), 256, 0, stream>>>(ns, wpb + 512*128, P1t, P2t);
  ec_kernel<<<NEDGES/64, 256, 0, stream>>>(ef, wcb + 256*64, Ec);
  gather_agg_kernel<<<NNODES/4, 256, 0, stream>>>(Ec, P1t, P2t, br1,
      start_from, eid_from, to_idx, aggh_r);

  // ---- attention (writes into freed Ec region) ----
  attn_kernel<<<512, 256, 0, stream>>>(ns, attn);

  // ---- agg second layer + node MLP ----
  agg_gemm_kernel<<<NNODES/64, 256, 0, stream>>>(aggh_f, aggh_r, wm2b, bm2, wr2b, br2,
                                                 start_to, start_from, aggb);

  node_mlp_kernel<<<NNODES/64, 256, 0, stream>>>(aggb, attn, ns,
      wn1b, bn1, wn2b, bn2, (float*)d_out);
}

// Round 4
// 730.618 us; speedup vs baseline: 2.0940x; 1.1403x over previous
//
#include <hip/hip_runtime.h>

typedef __bf16 bf16_t;
typedef __bf16 bf16x8 __attribute__((ext_vector_type(8)));
typedef __bf16 bf16x4 __attribute__((ext_vector_type(4)));
typedef float  f32x4  __attribute__((ext_vector_type(4)));

#define MFMA16(a,b,c) __builtin_amdgcn_mfma_f32_16x16x32_bf16((a),(b),(c),0,0,0)

constexpr int NNODES = 32768;
constexpr int NEDGES = 262144;
constexpr int DD = 128;
constexpr int HH = 256;

__device__ __forceinline__ bf16x8 cvt8(f32x4 a, f32x4 b){
  bf16x8 r;
  r[0]=(bf16_t)a[0]; r[1]=(bf16_t)a[1]; r[2]=(bf16_t)a[2]; r[3]=(bf16_t)a[3];
  r[4]=(bf16_t)b[0]; r[5]=(bf16_t)b[1]; r[6]=(bf16_t)b[2]; r[7]=(bf16_t)b[3];
  return r;
}

__global__ void cvt_kernel(const float* __restrict__ in, bf16_t* __restrict__ out, int n){
  int i = (blockIdx.x*256 + threadIdx.x)*4;
  if (i < n){
    f32x4 v = *(const f32x4*)(in + i);
    bf16x4 o; o[0]=(bf16_t)v[0]; o[1]=(bf16_t)v[1]; o[2]=(bf16_t)v[2]; o[3]=(bf16_t)v[3];
    *(bf16x4*)(out + i) = o;
  }
}

// wpb[1024][128]: rows 0..255 = Wm1[:,0:128], 256..511 = Wm1[:,128:256],
//                 512..767 = Wr1[:,0:128], 768..1023 = Wr1[:,128:256]
__global__ void cvt_wp_kernel(const float* __restrict__ Wm1, const float* __restrict__ Wr1,
                              bf16_t* __restrict__ wp){
  int idx = (blockIdx.x*256 + threadIdx.x)*4;   // < 131072
  int n = idx >> 7, k = idx & 127;
  const float* W = (n < 512) ? Wm1 : Wr1;
  int row = n & 255;
  int colbase = ((n >> 8) & 1) * 128;
  f32x4 v = *(const f32x4*)(W + (size_t)row*320 + colbase + k);
  bf16x4 o; o[0]=(bf16_t)v[0]; o[1]=(bf16_t)v[1]; o[2]=(bf16_t)v[2]; o[3]=(bf16_t)v[3];
  *(bf16x4*)(wp + idx) = o;
}

// wcb[512][64]: rows 0..255 = Wm1[:,256:320], 256..511 = Wr1[:,256:320]
__global__ void cvt_wc_kernel(const float* __restrict__ Wm1, const float* __restrict__ Wr1,
                              bf16_t* __restrict__ wc){
  int idx = (blockIdx.x*256 + threadIdx.x)*4;   // < 32768
  int n = idx >> 6, k = idx & 63;
  const float* W = (n < 256) ? Wm1 : Wr1;
  int row = n & 255;
  f32x4 v = *(const f32x4*)(W + (size_t)row*320 + 256 + k);
  bf16x4 o; o[0]=(bf16_t)v[0]; o[1]=(bf16_t)v[1]; o[2]=(bf16_t)v[2]; o[3]=(bf16_t)v[3];
  *(bf16x4*)(wc + idx) = o;
}

// ---------------- CSR build ----------------
__global__ void hist_kernel(const int* __restrict__ to_idx, const int* __restrict__ from_idx,
                            int* __restrict__ cnt_to, int* __restrict__ cnt_from){
  int e = blockIdx.x*256 + threadIdx.x;
  if (e < NEDGES){
    atomicAdd(&cnt_to[to_idx[e]], 1);
    atomicAdd(&cnt_from[from_idx[e]], 1);
  }
}

__global__ void scan_kernel(int* __restrict__ cnt, int* __restrict__ start){
  __shared__ int sums[1024];
  const int t = threadIdx.x;
  int local[32]; int s = 0;
  #pragma unroll
  for (int j=0;j<32;j++){ local[j] = cnt[t*32+j]; s += local[j]; }
  sums[t] = s; __syncthreads();
  #pragma unroll
  for (int d=1; d<1024; d<<=1){
    int v = (t>=d) ? sums[t-d] : 0;
    __syncthreads();
    sums[t] += v;
    __syncthreads();
  }
  int off = sums[t] - s;
  #pragma unroll
  for (int j=0;j<32;j++){
    start[t*32+j] = off;
    cnt[t*32+j]   = off;
    off += local[j];
  }
  if (t == 1023) start[32768] = sums[1023];
}

__global__ void place_kernel(const int* __restrict__ to_idx, const int* __restrict__ from_idx,
                             int* __restrict__ cur_to, int* __restrict__ cur_from,
                             int* __restrict__ eid_to, int* __restrict__ eid_from){
  int e = blockIdx.x*256 + threadIdx.x;
  if (e < NEDGES){
    int p = atomicAdd(&cur_to[to_idx[e]], 1);
    eid_to[p] = e;
    int q = atomicAdd(&cur_from[from_idx[e]], 1);
    eid_from[q] = e;
  }
}

// ---------------- node projections: P = ns @ Wblock^T (K=128) ----------------
__global__ __launch_bounds__(256,3) void proj_kernel(
    const float* __restrict__ ns, const bf16_t* __restrict__ Wp,
    bf16_t* __restrict__ P1, bf16_t* __restrict__ P2)
{
  constexpr int XS = 136;
  constexpr int CS = 264;
  __shared__ bf16_t Xs[64*XS];
  __shared__ bf16_t Cs[64*CS];
  const int tid = threadIdx.x;
  const int rb = blockIdx.x*64;
  const int cb = blockIdx.y;
  #pragma unroll
  for (int it=0; it<8; ++it){
    int c = tid + it*256;
    int row = c >> 5, co = (c & 31)*4;
    f32x4 v = *(const f32x4*)(ns + (size_t)(rb+row)*DD + co);
    bf16x4 o; o[0]=(bf16_t)v[0]; o[1]=(bf16_t)v[1]; o[2]=(bf16_t)v[2]; o[3]=(bf16_t)v[3];
    *(bf16x4*)&Xs[row*XS + co] = o;
  }
  __syncthreads();
  const int lane = tid & 63, wave = tid >> 6, lr = lane & 15, lk = lane >> 4;
  const bf16_t* Wb = Wp + (size_t)cb*256*128;
  f32x4 acc[16];
  #pragma unroll
  for (int nt=0;nt<16;nt++) acc[nt] = (f32x4){0.f,0.f,0.f,0.f};
  #pragma unroll
  for (int kc=0;kc<4;kc++){
    bf16x8 a = *(const bf16x8*)&Xs[(wave*16 + lr)*XS + kc*32 + lk*8];
    #pragma unroll
    for (int nt=0;nt<16;nt++){
      bf16x8 b = *(const bf16x8*)&Wb[(size_t)(nt*16 + lr)*128 + kc*32 + lk*8];
      acc[nt] = MFMA16(a,b,acc[nt]);
    }
  }
  #pragma unroll
  for (int nt=0;nt<16;nt++)
    #pragma unroll
    for (int r=0;r<4;r++)
      Cs[(wave*16 + lk*4 + r)*CS + nt*16 + lr] = (bf16_t)acc[nt][r];
  __syncthreads();
  bf16_t* P = cb ? P2 : P1;
  #pragma unroll
  for (int it=0; it<8; ++it){
    int c = tid + it*256;
    int row = c >> 5, co = (c & 31)*8;
    *(bf16x8*)&P[(size_t)(rb+row)*HH + co] = *(const bf16x8*)&Cs[row*CS + co];
  }
}

// ---------------- edge projection in CSR order: Ec[i] = ef[eid[i]] @ Wc^T ----------------
__global__ __launch_bounds__(256,3) void ec_kernel(
    const float* __restrict__ ef, const bf16_t* __restrict__ Wc,
    const int* __restrict__ eid, bf16_t* __restrict__ Ec)
{
  constexpr int XS = 72;
  constexpr int CS = 264;
  __shared__ bf16_t Xs[64*XS];
  __shared__ bf16_t Cs[64*CS];
  __shared__ int es[64];
  const int tid = threadIdx.x;
  const int rb = blockIdx.x*64;
  if (tid < 64) es[tid] = eid[rb + tid];
  __syncthreads();
  {
    const int row = tid>>2, part = tid&3;
    const float* s2 = ef + (size_t)es[row]*64 + part*16;
    #pragma unroll
    for (int j=0;j<4;j++){
      f32x4 v = *(const f32x4*)(s2 + j*4);
      bf16x4 o; o[0]=(bf16_t)v[0]; o[1]=(bf16_t)v[1]; o[2]=(bf16_t)v[2]; o[3]=(bf16_t)v[3];
      *(bf16x4*)&Xs[row*XS + part*16 + j*4] = o;
    }
  }
  __syncthreads();
  const int lane = tid & 63, wave = tid >> 6, lr = lane & 15, lk = lane >> 4;
  f32x4 acc[16];
  #pragma unroll
  for (int nt=0;nt<16;nt++) acc[nt] = (f32x4){0.f,0.f,0.f,0.f};
  #pragma unroll
  for (int kc=0;kc<2;kc++){
    bf16x8 a = *(const bf16x8*)&Xs[(wave*16 + lr)*XS + kc*32 + lk*8];
    #pragma unroll
    for (int nt=0;nt<16;nt++){
      bf16x8 b = *(const bf16x8*)&Wc[(size_t)(nt*16 + lr)*64 + kc*32 + lk*8];
      acc[nt] = MFMA16(a,b,acc[nt]);
    }
  }
  #pragma unroll
  for (int nt=0;nt<16;nt++)
    #pragma unroll
    for (int r=0;r<4;r++)
      Cs[(wave*16 + lk*4 + r)*CS + nt*16 + lr] = (bf16_t)acc[nt][r];
  __syncthreads();
  #pragma unroll
  for (int it=0; it<8; ++it){
    int c = tid + it*256;
    int row = c >> 5, co = (c & 31)*8;
    *(bf16x8*)&Ec[(size_t)(rb+row)*HH + co] = *(const bf16x8*)&Cs[row*CS + co];
  }
}

// ---------------- fused combine + aggregate; Ec streamed in CSR order ----------------
__global__ __launch_bounds__(256) void gather_agg_kernel(
    const bf16_t* __restrict__ Ec, const bf16_t* __restrict__ P1,
    const bf16_t* __restrict__ P2, const float* __restrict__ b1,
    const int* __restrict__ start, const int* __restrict__ eid,
    const int* __restrict__ oth, bf16_t* __restrict__ aggh)
{
  const int wave = threadIdx.x >> 6;
  const int lane = threadIdx.x & 63;
  const int half = lane >> 5;
  const int l32  = lane & 31;
  const int c0 = l32*8;
  const int v = blockIdx.x*4 + wave;
  float base[8];
  {
    bf16x8 p2 = *(const bf16x8*)&P2[(size_t)v*HH + c0];
    f32x4 b0 = *(const f32x4*)(b1 + c0);
    f32x4 b4 = *(const f32x4*)(b1 + c0 + 4);
    #pragma unroll
    for (int j=0;j<4;j++){ base[j] = (float)p2[j] + b0[j]; base[4+j] = (float)p2[4+j] + b4[j]; }
  }
  float acc[8] = {0.f,0.f,0.f,0.f,0.f,0.f,0.f,0.f};
  const int s = start[v], e_end = start[v+1];
  for (int i = s + half; i < e_end; i += 2){
    const int eg = eid[i];
    const int o  = oth[eg];
    bf16x8 ec = *(const bf16x8*)&Ec[(size_t)i*HH + c0];
    bf16x8 p1 = *(const bf16x8*)&P1[(size_t)o*HH + c0];
    #pragma unroll
    for (int j=0;j<8;j++){
      float x = base[j] + (float)ec[j] + (float)p1[j];
      acc[j] += fmaxf(x, 0.f);
    }
  }
  #pragma unroll
  for (int j=0;j<8;j++) acc[j] += __shfl(acc[j], lane ^ 32);
  if (half == 0){
    bf16x8 o8;
    #pragma unroll
    for (int j=0;j<8;j++) o8[j] = (bf16_t)acc[j];
    *(bf16x8*)&aggh[(size_t)v*HH + c0] = o8;
  }
}

// ---------------- agg GEMM ----------------
__global__ __launch_bounds__(256,2) void agg_gemm_kernel(
    const bf16_t* __restrict__ aggh_f, const bf16_t* __restrict__ aggh_r,
    const bf16_t* __restrict__ Wm2, const float* __restrict__ bm2,
    const bf16_t* __restrict__ Wr2, const float* __restrict__ br2,
    const int* __restrict__ start_to, const int* __restrict__ start_from,
    bf16_t* __restrict__ agg)
{
  constexpr int HS = 264;
  __shared__ bf16_t Af[64*HS];
  __shared__ bf16_t Ar[64*HS];
  const int tid = threadIdx.x;
  const int rb = blockIdx.x*64;
  #pragma unroll
  for (int it=0; it<8; ++it){
    int c = tid + it*256;
    int row = c >> 5;
    int co  = (c & 31) * 8;
    *(bf16x8*)&Af[row*HS+co] = *(const bf16x8*)&aggh_f[(size_t)(rb+row)*HH + co];
    *(bf16x8*)&Ar[row*HS+co] = *(const bf16x8*)&aggh_r[(size_t)(rb+row)*HH + co];
  }
  __syncthreads();

  const int lane = tid & 63, wave = tid >> 6, lr = lane & 15, lk = lane >> 4;
  f32x4 acc[16];
  #pragma unroll
  for (int nt=0;nt<16;nt++) acc[nt] = (f32x4){0.f,0.f,0.f,0.f};
  #pragma unroll
  for (int kc=0;kc<8;kc++){
    bf16x8 a = *(const bf16x8*)&Af[(wave*16 + lr)*HS + kc*32 + lk*8];
    #pragma unroll
    for (int nt=0;nt<16;nt++){
      bf16x8 b = *(const bf16x8*)&Wm2[(size_t)(nt*16 + lr)*HH + kc*32 + lk*8];
      acc[nt] = MFMA16(a,b,acc[nt]);
    }
  }
  #pragma unroll
  for (int kc=0;kc<8;kc++){
    bf16x8 a = *(const bf16x8*)&Ar[(wave*16 + lr)*HS + kc*32 + lk*8];
    #pragma unroll
    for (int nt=0;nt<16;nt++){
      bf16x8 b = *(const bf16x8*)&Wr2[(size_t)(nt*16 + lr)*HH + kc*32 + lk*8];
      acc[nt] = MFMA16(a,b,acc[nt]);
    }
  }
  #pragma unroll
  for (int nt=0;nt<16;nt++){
    const int col = nt*16 + lr;
    const float bm = bm2[col], br = br2[col];
    #pragma unroll
    for (int r=0;r<4;r++){
      const int row = rb + wave*16 + lk*4 + r;
      const float dt = (float)(start_to[row+1]   - start_to[row]);
      const float df = (float)(start_from[row+1] - start_from[row]);
      agg[(size_t)row*HH + col] = (bf16_t)(acc[nt][r] + dt*bm + df*br);
    }
  }
}

// ---------------- nsT: d-major, slot-permuted transpose of ns (bf16) ----------------
// nsT[sb][d][t*32 + s] = ns[sb*2048 + t*32 + m(s)][d], m(s) = s even ? s/2 : 16+s/2
__global__ __launch_bounds__(256) void nst_kernel(const float* __restrict__ ns, bf16_t* __restrict__ nsT){
  constexpr int XS2 = 136;
  __shared__ bf16_t Xs[64*XS2];
  const int tid = threadIdx.x;
  const int nb = blockIdx.x*64;
  #pragma unroll
  for (int it=0; it<8; ++it){
    int c = tid + it*256;
    int rowl = c >> 5, co = (c & 31)*4;
    f32x4 v = *(const f32x4*)(ns + (size_t)(nb+rowl)*DD + co);
    bf16x4 o; o[0]=(bf16_t)v[0]; o[1]=(bf16_t)v[1]; o[2]=(bf16_t)v[2]; o[3]=(bf16_t)v[3];
    *(bf16x4*)&Xs[rowl*XS2 + co] = o;
  }
  __syncthreads();
  const int sb = nb >> 11;
  const int jb = nb & 2047;
  bf16_t* outp = nsT + (size_t)sb*DD*2048 + jb;
  #pragma unroll
  for (int it=0; it<4; ++it){
    int c = tid + it*256;
    int d = c >> 3, g8 = (c & 7)*8;
    bf16x8 o;
    #pragma unroll
    for (int k=0;k<8;k++){
      int s64 = g8 + k;
      int t32 = s64 >> 5, s = s64 & 31;
      int m = (s & 1) ? (16 + (s>>1)) : (s>>1);
      o[k] = Xs[(t32*32 + m)*XS2 + d];
    }
    *(bf16x8*)(outp + (size_t)d*2048 + g8) = o;
  }
}

// ---------------- cross-graph attention: no-max softmax, dbuf, conflict-free LDS ----------------
__global__ __launch_bounds__(256,2) void attn_kernel(
    const bf16_t* __restrict__ nsB, const bf16_t* __restrict__ nsT,
    const float* __restrict__ ns, float* __restrict__ attn)
{
  constexpr int KS = 136;
  constexpr int VS = 40;
  constexpr int PS = 40;
  __shared__ bf16_t Ks[2][32*KS];
  __shared__ bf16_t Vt[2][128*VS];
  __shared__ bf16_t Ps[64*PS];
  const int tid = threadIdx.x;
  const int lane = tid & 63, wave = tid >> 6, lr = lane & 15, lk = lane >> 4;
  const int bx = blockIdx.x;
  const int qt = bx & 31, side = (bx>>5)&1, p = bx>>6;
  const size_t qbase = (size_t)p*4096 + (size_t)side*2048 + (size_t)qt*64;
  const int sbkv = p*2 + (side^1);
  const bf16_t* Kv = nsB + ((size_t)p*4096 + (size_t)(side^1)*2048)*DD;
  const bf16_t* Vp = nsT + (size_t)sbkv*DD*2048;

  bf16x8 qf[4];
  {
    const bf16_t* qrow = nsB + (qbase + wave*16 + lr)*DD;
    #pragma unroll
    for (int kc=0;kc<4;kc++) qf[kc] = *(const bf16x8*)(qrow + kc*32 + lk*8);
  }
  float ls[4] = {0.f,0.f,0.f,0.f};
  f32x4 acco[8];
  #pragma unroll
  for (int nt=0;nt<8;nt++) acco[nt]=(f32x4){0.f,0.f,0.f,0.f};

  const int krow0 = tid>>4,        kcol = (tid&15)*8;
  const int vd0   = tid>>2,        vsl  = (tid&3)*8;
  bf16x8 kreg0, kreg1, vreg0, vreg1;

  auto load_tile = [&](int t){
    const bf16_t* kp = Kv + (size_t)t*32*DD;
    kreg0 = *(const bf16x8*)(kp + (size_t)krow0*DD + kcol);
    kreg1 = *(const bf16x8*)(kp + (size_t)(krow0+16)*DD + kcol);
    const bf16_t* vp = Vp + t*32;
    vreg0 = *(const bf16x8*)(vp + (size_t)vd0*2048 + vsl);
    vreg1 = *(const bf16x8*)(vp + (size_t)(vd0+64)*2048 + vsl);
  };
  auto store_tile = [&](int b){
    *(bf16x8*)&Ks[b][krow0*KS + kcol]      = kreg0;
    *(bf16x8*)&Ks[b][(krow0+16)*KS + kcol] = kreg1;
    *(bf16x8*)&Vt[b][vd0*VS + vsl]         = vreg0;
    *(bf16x8*)&Vt[b][(vd0+64)*VS + vsl]    = vreg1;
  };

  load_tile(0);
  store_tile(0);
  load_tile(1);
  __syncthreads();
  int cur = 0;
  for (int t=0; t<64; ++t){
    if (t+1 < 64){
      store_tile(cur^1);
      if (t+2 < 64) load_tile(t+2);
    }
    f32x4 s0 = (f32x4){0.f,0.f,0.f,0.f}, s1 = (f32x4){0.f,0.f,0.f,0.f};
    #pragma unroll
    for (int kc=0;kc<4;kc++){
      bf16x8 b0 = *(const bf16x8*)&Ks[cur][lr*KS      + kc*32 + lk*8];
      bf16x8 b1 = *(const bf16x8*)&Ks[cur][(16+lr)*KS + kc*32 + lk*8];
      s0 = MFMA16(qf[kc], b0, s0);
      s1 = MFMA16(qf[kc], b1, s1);
    }
    #pragma unroll
    for (int r=0;r<4;r++){
      float p0 = __expf(s0[r] - 40.f);
      float p1 = __expf(s1[r] - 40.f);
      ls[r] += p0 + p1;
      union { bf16_t h[2]; unsigned u; } pk;
      pk.h[0] = (bf16_t)p0; pk.h[1] = (bf16_t)p1;
      *(unsigned*)&Ps[(wave*16 + lk*4 + r)*PS + 2*lr] = pk.u;
    }
    asm volatile("s_waitcnt lgkmcnt(0)" ::: "memory");
    __builtin_amdgcn_sched_barrier(0);
    bf16x8 pa = *(const bf16x8*)&Ps[(wave*16 + lr)*PS + lk*8];
    #pragma unroll
    for (int nt=0;nt<8;nt++){
      bf16x8 vb = *(const bf16x8*)&Vt[cur][(nt*16+lr)*VS + lk*8];
      acco[nt] = MFMA16(pa, vb, acco[nt]);
    }
    __syncthreads();
    cur ^= 1;
  }
  #pragma unroll
  for (int r=0;r<4;r++){
    float v = ls[r];
    v += __shfl_xor(v,1); v += __shfl_xor(v,2);
    v += __shfl_xor(v,4); v += __shfl_xor(v,8);
    ls[r] = 1.f/v;
  }
  #pragma unroll
  for (int nt=0;nt<8;nt++){
    const int col = nt*16 + lr;
    #pragma unroll
    for (int r=0;r<4;r++){
      const size_t row = qbase + wave*16 + lk*4 + r;
      attn[row*DD + col] = ns[row*DD + col] - acco[nt][r]*ls[r];
    }
  }
}

// ---------------- node MLP + residual ----------------
__global__ __launch_bounds__(256,4) void node_mlp_kernel(
    const bf16_t* __restrict__ aggb, const float* __restrict__ attn,
    const float* __restrict__ ns,
    const bf16_t* __restrict__ Wn1b, const float* __restrict__ bn1,
    const bf16_t* __restrict__ Wn2b, const float* __restrict__ bn2,
    float* __restrict__ out)
{
  constexpr int HS = 264;
  __shared__ bf16_t Hs[64*HS];
  const int tid = threadIdx.x;
  const int lane = tid & 63, wave = tid >> 6, lr = lane & 15, lk = lane >> 4;
  const int rb = blockIdx.x*64;
  const int row = rb + wave*16 + lr;

  f32x4 acc[16];
  #pragma unroll
  for (int nt=0;nt<16;nt++) acc[nt] = (f32x4){0.f,0.f,0.f,0.f};
  #pragma unroll
  for (int kc=0;kc<8;kc++){
    bf16x8 a = *(const bf16x8*)&aggb[(size_t)row*HH + kc*32 + lk*8];
    #pragma unroll
    for (int nt=0;nt<16;nt++){
      bf16x8 b = *(const bf16x8*)&Wn1b[(size_t)(nt*16 + lr)*512 + kc*32 + lk*8];
      acc[nt] = MFMA16(a,b,acc[nt]);
    }
  }
  #pragma unroll
  for (int kc=8;kc<16;kc++){
    const float* s; int col;
    if (kc <12) { s = attn + (size_t)row*DD; col = kc*32 + lk*8 - 256; }
    else        { s = ns   + (size_t)row*DD; col = kc*32 + lk*8 - 384; }
    f32x4 v0 = *(const f32x4*)(s + col);
    f32x4 v1 = *(const f32x4*)(s + col + 4);
    bf16x8 a = cvt8(v0,v1);
    #pragma unroll
    for (int nt=0;nt<16;nt++){
      bf16x8 b = *(const bf16x8*)&Wn1b[(size_t)(nt*16 + lr)*512 + kc*32 + lk*8];
      acc[nt] = MFMA16(a,b,acc[nt]);
    }
  }
  #pragma unroll
  for (int nt=0;nt<16;nt++){
    float bias = bn1[nt*16 + lr];
    #pragma unroll
    for (int r=0;r<4;r++){
      float v = acc[nt][r] + bias;
      v = v > 0.f ? v : 0.f;
      Hs[(wave*16 + lk*4 + r)*HS + nt*16 + lr] = (bf16_t)v;
    }
  }
  asm volatile("s_waitcnt lgkmcnt(0)" ::: "memory");
  __builtin_amdgcn_sched_barrier(0);

  f32x4 acc2[8];
  #pragma unroll
  for (int nt=0;nt<8;nt++) acc2[nt] = (f32x4){0.f,0.f,0.f,0.f};
  #pragma unroll
  for (int kc=0;kc<8;kc++){
    bf16x8 a = *(const bf16x8*)&Hs[(wave*16 + lr)*HS + kc*32 + lk*8];
    #pragma unroll
    for (int nt=0;nt<8;nt++){
      bf16x8 b = *(const bf16x8*)&Wn2b[(size_t)(nt*16 + lr)*HH + kc*32 + lk*8];
      acc2[nt] = MFMA16(a,b,acc2[nt]);
    }
  }
  const int r0 = rb + wave*16 + lk*4;
  #pragma unroll
  for (int nt=0;nt<8;nt++){
    const int col = nt*16 + lr;
    const float bias = bn2[col];
    #pragma unroll
    for (int r=0;r<4;r++){
      const size_t rr = (size_t)(r0 + r);
      out[rr*DD + col] = acc2[nt][r] + bias + ns[rr*DD + col];
    }
  }
}

extern "C" void kernel_launch(void* const* d_in, const int* in_sizes, int n_in,
                              void* d_out, int out_size, void* d_ws, size_t ws_size,
                              hipStream_t stream) {
  const float* ns  = (const float*)d_in[0];
  const float* ef  = (const float*)d_in[1];
  const int* from_idx = (const int*)d_in[2];
  const int* to_idx   = (const int*)d_in[3];
  const float* Wm1 = (const float*)d_in[6];  const float* bm1 = (const float*)d_in[7];
  const float* Wm2 = (const float*)d_in[8];  const float* bm2 = (const float*)d_in[9];
  const float* Wr1 = (const float*)d_in[10]; const float* br1 = (const float*)d_in[11];
  const float* Wr2 = (const float*)d_in[12]; const float* br2 = (const float*)d_in[13];
  const float* Wn1 = (const float*)d_in[14]; const float* bn1 = (const float*)d_in[15];
  const float* Wn2 = (const float*)d_in[16]; const float* bn2 = (const float*)d_in[17];

  char* ws = (char*)d_ws;
  bf16_t* Ec     = (bf16_t*)(ws);                      // 134,217,728
  bf16_t* P1t    = (bf16_t*)(ws + 134217728);
  bf16_t* P2t    = (bf16_t*)(ws + 150994944);
  bf16_t* aggh_f = (bf16_t*)(ws + 167772160);
  bf16_t* aggh_r = (bf16_t*)(ws + 184549376);
  bf16_t* wpb  = (bf16_t*)(ws + 201326592);
  bf16_t* wcb  = (bf16_t*)(ws + 201588736);
  bf16_t* wm2b = (bf16_t*)(ws + 201654272);
  bf16_t* wr2b = (bf16_t*)(ws + 201785344);
  bf16_t* wn1b = (bf16_t*)(ws + 201916416);
  bf16_t* wn2b = (bf16_t*)(ws + 202178560);
  int* cur_to     = (int*)(ws + 202244096);
  int* cur_from   = (int*)(ws + 202375168);
  int* start_to   = (int*)(ws + 202506240);
  int* start_from = (int*)(ws + 202637320);
  int* eid_to     = (int*)(ws + 202768400);
  int* eid_from   = (int*)(ws + 203816976);
  // Ec region reused after gather passes:
  float*  attn = (float*) (ws);                        // 16 MB
  bf16_t* aggb = (bf16_t*)(ws + 16777216);             // 16 MB
  bf16_t* nsB  = (bf16_t*)(ws + 33554432);             // 8 MB
  bf16_t* nsT  = (bf16_t*)(ws + 41943040);             // 8 MB

  hipMemsetAsync(cur_to, 0, 2*NNODES*sizeof(int), stream);

  cvt_wp_kernel<<<128, 256, 0, stream>>>(Wm1, Wr1, wpb);
  cvt_wc_kernel<<<32, 256, 0, stream>>>(Wm1, Wr1, wcb);
  cvt_kernel<<<64, 256, 0, stream>>>(Wm2, wm2b, 256*256);
  cvt_kernel<<<64, 256, 0, stream>>>(Wr2, wr2b, 256*256);
  cvt_kernel<<<128,256, 0, stream>>>(Wn1, wn1b, 256*512);
  cvt_kernel<<<32, 256, 0, stream>>>(Wn2, wn2b, 128*256);

  hist_kernel<<<NEDGES/256, 256, 0, stream>>>(to_idx, from_idx, cur_to, cur_from);
  scan_kernel<<<1, 1024, 0, stream>>>(cur_to, start_to);
  scan_kernel<<<1, 1024, 0, stream>>>(cur_from, start_from);
  place_kernel<<<NEDGES/256, 256, 0, stream>>>(to_idx, from_idx, cur_to, cur_from, eid_to, eid_from);

  // forward: h = relu(Pa[from] + Pb[to] + Ec + bm1), aggregate at to
  proj_kernel<<<dim3(NNODES/64, 2), 256, 0, stream>>>(ns, wpb, P1t, P2t);
  ec_kernel<<<NEDGES/64, 256, 0, stream>>>(ef, wcb, eid_to, Ec);
  gather_agg_kernel<<<NNODES/4, 256, 0, stream>>>(Ec, P1t, P2t, bm1,
      start_to, eid_to, from_idx, aggh_f);

  // reverse: aggregate at from
  proj_kernel<<<dim3(NNODES/64, 2), 256, 0, stream>>>(ns, wpb + 512*128, P1t, P2t);
  ec_kernel<<<NEDGES/64, 256, 0, stream>>>(ef, wcb + 256*64, eid_from, Ec);
  gather_agg_kernel<<<NNODES/4, 256, 0, stream>>>(Ec, P1t, P2t, br1,
      start_from, eid_from, to_idx, aggh_r);

  // attention prep (Ec region now dead) + attention
  cvt_kernel<<<4096, 256, 0, stream>>>(ns, nsB, NNODES*DD);
  nst_kernel<<<NNODES/64, 256, 0, stream>>>(ns, nsT);
  attn_kernel<<<512, 256, 0, stream>>>(nsB, nsT, ns, attn);

  // agg second layer + node MLP
  agg_gemm_kernel<<<NNODES/64, 256, 0, stream>>>(aggh_f, aggh_r, wm2b, bm2, wr2b, br2,
                                                 start_to, start_from, aggb);

  node_mlp_kernel<<<NNODES/64, 256, 0, stream>>>(aggb, attn, ns,
      wn1b, bn1, wn2b, bn2, (float*)d_out);
}

// Round 5
// 646.151 us; speedup vs baseline: 2.3677x; 1.1307x over previous
//
#include <hip/hip_runtime.h>

typedef __bf16 bf16_t;
typedef __bf16 bf16x8 __attribute__((ext_vector_type(8)));
typedef __bf16 bf16x4 __attribute__((ext_vector_type(4)));
typedef float  f32x4  __attribute__((ext_vector_type(4)));

#define MFMA16(a,b,c) __builtin_amdgcn_mfma_f32_16x16x32_bf16((a),(b),(c),0,0,0)

constexpr int NNODES = 32768;
constexpr int NEDGES = 262144;
constexpr int DD = 128;
constexpr int HH = 256;

__device__ __forceinline__ bf16x8 cvt8(f32x4 a, f32x4 b){
  bf16x8 r;
  r[0]=(bf16_t)a[0]; r[1]=(bf16_t)a[1]; r[2]=(bf16_t)a[2]; r[3]=(bf16_t)a[3];
  r[4]=(bf16_t)b[0]; r[5]=(bf16_t)b[1]; r[6]=(bf16_t)b[2]; r[7]=(bf16_t)b[3];
  return r;
}

__global__ void cvt_kernel(const float* __restrict__ in, bf16_t* __restrict__ out, int n){
  int i = (blockIdx.x*256 + threadIdx.x)*4;
  if (i < n){
    f32x4 v = *(const f32x4*)(in + i);
    bf16x4 o; o[0]=(bf16_t)v[0]; o[1]=(bf16_t)v[1]; o[2]=(bf16_t)v[2]; o[3]=(bf16_t)v[3];
    *(bf16x4*)(out + i) = o;
  }
}

// wpb[1024][128]: rows 0..255 = Wm1[:,0:128], 256..511 = Wm1[:,128:256],
//                 512..767 = Wr1[:,0:128], 768..1023 = Wr1[:,128:256]
__global__ void cvt_wp_kernel(const float* __restrict__ Wm1, const float* __restrict__ Wr1,
                              bf16_t* __restrict__ wp){
  int idx = (blockIdx.x*256 + threadIdx.x)*4;
  int n = idx >> 7, k = idx & 127;
  const float* W = (n < 512) ? Wm1 : Wr1;
  int row = n & 255;
  int colbase = ((n >> 8) & 1) * 128;
  f32x4 v = *(const f32x4*)(W + (size_t)row*320 + colbase + k);
  bf16x4 o; o[0]=(bf16_t)v[0]; o[1]=(bf16_t)v[1]; o[2]=(bf16_t)v[2]; o[3]=(bf16_t)v[3];
  *(bf16x4*)(wp + idx) = o;
}

// wcb[512][64]: rows 0..255 = Wm1[:,256:320], 256..511 = Wr1[:,256:320]
__global__ void cvt_wc_kernel(const float* __restrict__ Wm1, const float* __restrict__ Wr1,
                              bf16_t* __restrict__ wc){
  int idx = (blockIdx.x*256 + threadIdx.x)*4;
  int n = idx >> 6, k = idx & 63;
  const float* W = (n < 256) ? Wm1 : Wr1;
  int row = n & 255;
  f32x4 v = *(const f32x4*)(W + (size_t)row*320 + 256 + k);
  bf16x4 o; o[0]=(bf16_t)v[0]; o[1]=(bf16_t)v[1]; o[2]=(bf16_t)v[2]; o[3]=(bf16_t)v[3];
  *(bf16x4*)(wc + idx) = o;
}

// ---------------- CSR build ----------------
__global__ void hist_kernel(const int* __restrict__ to_idx, const int* __restrict__ from_idx,
                            int* __restrict__ cnt_to, int* __restrict__ cnt_from){
  int e = blockIdx.x*256 + threadIdx.x;
  if (e < NEDGES){
    atomicAdd(&cnt_to[to_idx[e]], 1);
    atomicAdd(&cnt_from[from_idx[e]], 1);
  }
}

__global__ void scan_kernel(int* __restrict__ cnt, int* __restrict__ start){
  __shared__ int sums[1024];
  const int t = threadIdx.x;
  int local[32]; int s = 0;
  #pragma unroll
  for (int j=0;j<32;j++){ local[j] = cnt[t*32+j]; s += local[j]; }
  sums[t] = s; __syncthreads();
  #pragma unroll
  for (int d=1; d<1024; d<<=1){
    int v = (t>=d) ? sums[t-d] : 0;
    __syncthreads();
    sums[t] += v;
    __syncthreads();
  }
  int off = sums[t] - s;
  #pragma unroll
  for (int j=0;j<32;j++){
    start[t*32+j] = off;
    cnt[t*32+j]   = off;
    off += local[j];
  }
  if (t == 1023) start[32768] = sums[1023];
}

__global__ void place_kernel(const int* __restrict__ to_idx, const int* __restrict__ from_idx,
                             int* __restrict__ cur_to, int* __restrict__ cur_from,
                             int* __restrict__ eid_to, int* __restrict__ eid_from){
  int e = blockIdx.x*256 + threadIdx.x;
  if (e < NEDGES){
    int p = atomicAdd(&cur_to[to_idx[e]], 1);
    eid_to[p] = e;
    int q = atomicAdd(&cur_from[from_idx[e]], 1);
    eid_from[q] = e;
  }
}

// ---------------- node projections: P = ns @ Wblock^T (K=128) ----------------
__global__ __launch_bounds__(256,3) void proj_kernel(
    const float* __restrict__ ns, const bf16_t* __restrict__ Wp,
    bf16_t* __restrict__ P1, bf16_t* __restrict__ P2)
{
  constexpr int XS = 136;
  constexpr int CS = 264;
  __shared__ bf16_t Xs[64*XS];
  __shared__ bf16_t Cs[64*CS];
  const int tid = threadIdx.x;
  const int rb = blockIdx.x*64;
  const int cb = blockIdx.y;
  #pragma unroll
  for (int it=0; it<8; ++it){
    int c = tid + it*256;
    int row = c >> 5, co = (c & 31)*4;
    f32x4 v = *(const f32x4*)(ns + (size_t)(rb+row)*DD + co);
    bf16x4 o; o[0]=(bf16_t)v[0]; o[1]=(bf16_t)v[1]; o[2]=(bf16_t)v[2]; o[3]=(bf16_t)v[3];
    *(bf16x4*)&Xs[row*XS + co] = o;
  }
  __syncthreads();
  const int lane = tid & 63, wave = tid >> 6, lr = lane & 15, lk = lane >> 4;
  const bf16_t* Wb = Wp + (size_t)cb*256*128;
  f32x4 acc[16];
  #pragma unroll
  for (int nt=0;nt<16;nt++) acc[nt] = (f32x4){0.f,0.f,0.f,0.f};
  #pragma unroll
  for (int kc=0;kc<4;kc++){
    bf16x8 a = *(const bf16x8*)&Xs[(wave*16 + lr)*XS + kc*32 + lk*8];
    #pragma unroll
    for (int nt=0;nt<16;nt++){
      bf16x8 b = *(const bf16x8*)&Wb[(size_t)(nt*16 + lr)*128 + kc*32 + lk*8];
      acc[nt] = MFMA16(a,b,acc[nt]);
    }
  }
  #pragma unroll
  for (int nt=0;nt<16;nt++)
    #pragma unroll
    for (int r=0;r<4;r++)
      Cs[(wave*16 + lk*4 + r)*CS + nt*16 + lr] = (bf16_t)acc[nt][r];
  __syncthreads();
  bf16_t* P = cb ? P2 : P1;
  #pragma unroll
  for (int it=0; it<8; ++it){
    int c = tid + it*256;
    int row = c >> 5, co = (c & 31)*8;
    *(bf16x8*)&P[(size_t)(rb+row)*HH + co] = *(const bf16x8*)&Cs[row*CS + co];
  }
}

// ---------------- edge projection in CSR order: Ec[i] = ef[eid[i]] @ Wc^T ----------------
__global__ __launch_bounds__(256,3) void ec_kernel(
    const float* __restrict__ ef, const bf16_t* __restrict__ Wc,
    const int* __restrict__ eid, bf16_t* __restrict__ Ec)
{
  constexpr int XS = 72;
  constexpr int CS = 264;
  __shared__ bf16_t Xs[64*XS];
  __shared__ bf16_t Cs[64*CS];
  __shared__ int es[64];
  const int tid = threadIdx.x;
  const int rb = blockIdx.x*64;
  if (tid < 64) es[tid] = eid[rb + tid];
  __syncthreads();
  {
    const int row = tid>>2, part = tid&3;
    const float* s2 = ef + (size_t)es[row]*64 + part*16;
    #pragma unroll
    for (int j=0;j<4;j++){
      f32x4 v = *(const f32x4*)(s2 + j*4);
      bf16x4 o; o[0]=(bf16_t)v[0]; o[1]=(bf16_t)v[1]; o[2]=(bf16_t)v[2]; o[3]=(bf16_t)v[3];
      *(bf16x4*)&Xs[row*XS + part*16 + j*4] = o;
    }
  }
  __syncthreads();
  const int lane = tid & 63, wave = tid >> 6, lr = lane & 15, lk = lane >> 4;
  f32x4 acc[16];
  #pragma unroll
  for (int nt=0;nt<16;nt++) acc[nt] = (f32x4){0.f,0.f,0.f,0.f};
  #pragma unroll
  for (int kc=0;kc<2;kc++){
    bf16x8 a = *(const bf16x8*)&Xs[(wave*16 + lr)*XS + kc*32 + lk*8];
    #pragma unroll
    for (int nt=0;nt<16;nt++){
      bf16x8 b = *(const bf16x8*)&Wc[(size_t)(nt*16 + lr)*64 + kc*32 + lk*8];
      acc[nt] = MFMA16(a,b,acc[nt]);
    }
  }
  #pragma unroll
  for (int nt=0;nt<16;nt++)
    #pragma unroll
    for (int r=0;r<4;r++)
      Cs[(wave*16 + lk*4 + r)*CS + nt*16 + lr] = (bf16_t)acc[nt][r];
  __syncthreads();
  #pragma unroll
  for (int it=0; it<8; ++it){
    int c = tid + it*256;
    int row = c >> 5, co = (c & 31)*8;
    *(bf16x8*)&Ec[(size_t)(rb+row)*HH + co] = *(const bf16x8*)&Cs[row*CS + co];
  }
}

// ---------------- fused combine + aggregate; Ec streamed in CSR order ----------------
__global__ __launch_bounds__(256) void gather_agg_kernel(
    const bf16_t* __restrict__ Ec, const bf16_t* __restrict__ P1,
    const bf16_t* __restrict__ P2, const float* __restrict__ b1,
    const int* __restrict__ start, const int* __restrict__ eid,
    const int* __restrict__ oth, bf16_t* __restrict__ aggh)
{
  const int wave = threadIdx.x >> 6;
  const int lane = threadIdx.x & 63;
  const int half = lane >> 5;
  const int l32  = lane & 31;
  const int c0 = l32*8;
  const int v = blockIdx.x*4 + wave;
  float base[8];
  {
    bf16x8 p2 = *(const bf16x8*)&P2[(size_t)v*HH + c0];
    f32x4 b0 = *(const f32x4*)(b1 + c0);
    f32x4 b4 = *(const f32x4*)(b1 + c0 + 4);
    #pragma unroll
    for (int j=0;j<4;j++){ base[j] = (float)p2[j] + b0[j]; base[4+j] = (float)p2[4+j] + b4[j]; }
  }
  float acc[8] = {0.f,0.f,0.f,0.f,0.f,0.f,0.f,0.f};
  const int s = start[v], e_end = start[v+1];
  for (int i = s + half; i < e_end; i += 2){
    const int eg = eid[i];
    const int o  = oth[eg];
    bf16x8 ec = *(const bf16x8*)&Ec[(size_t)i*HH + c0];
    bf16x8 p1 = *(const bf16x8*)&P1[(size_t)o*HH + c0];
    #pragma unroll
    for (int j=0;j<8;j++){
      float x = base[j] + (float)ec[j] + (float)p1[j];
      acc[j] += fmaxf(x, 0.f);
    }
  }
  #pragma unroll
  for (int j=0;j<8;j++) acc[j] += __shfl(acc[j], lane ^ 32);
  if (half == 0){
    bf16x8 o8;
    #pragma unroll
    for (int j=0;j<8;j++) o8[j] = (bf16_t)acc[j];
    *(bf16x8*)&aggh[(size_t)v*HH + c0] = o8;
  }
}

// ---------------- weight prep for fused node MLP ----------------
// transpose Wm2/Wr2 (f32 [256][256]) -> bf16 [k'][j]
__global__ __launch_bounds__(256) void w2t_kernel(const float* __restrict__ Wm2, const float* __restrict__ Wr2,
                                                  bf16_t* __restrict__ wm2T, bf16_t* __restrict__ wr2T){
  __shared__ bf16_t t[64][72];
  const int bi = (blockIdx.x & 3)*64;
  const int bj = ((blockIdx.x>>2) & 3)*64;
  const int m  = blockIdx.x >> 4;
  const float* W = m ? Wr2 : Wm2;
  bf16_t* WT = m ? wr2T : wm2T;
  const int tid = threadIdx.x;
  #pragma unroll
  for (int it=0; it<16; ++it){
    int c = tid + it*256;
    int r = c >> 6, co = c & 63;
    t[r][co] = (bf16_t)W[(size_t)(bi+r)*256 + bj + co];
  }
  __syncthreads();
  #pragma unroll
  for (int it=0; it<16; ++it){
    int c = tid + it*256;
    int r = c >> 6, co = c & 63;
    WT[(size_t)(bj+r)*256 + bi + co] = t[co][r];
  }
}

// wcat[:, cb*256 : cb*256+256] = Wn1[:,0:256] @ (cb? Wr2 : Wm2)   (C[n][k'] = sum_j Wn1a[n,j]*W2[j,k'])
__global__ __launch_bounds__(256,2) void wcat_gemm_kernel(
    const float* __restrict__ Wn1, const bf16_t* __restrict__ wm2T, const bf16_t* __restrict__ wr2T,
    bf16_t* __restrict__ wcat)
{
  constexpr int XS = 264, CS = 264;
  __shared__ bf16_t Xs[64*XS];
  __shared__ bf16_t Cs[64*CS];
  const int tid = threadIdx.x;
  const int rb = blockIdx.x*64;
  const int cb = blockIdx.y;
  const bf16_t* BT = cb ? wr2T : wm2T;
  #pragma unroll
  for (int it=0; it<16; ++it){
    int c = tid + it*256;
    int row = c >> 6, co = (c & 63)*4;
    f32x4 v = *(const f32x4*)(Wn1 + (size_t)(rb+row)*512 + co);
    bf16x4 o; o[0]=(bf16_t)v[0]; o[1]=(bf16_t)v[1]; o[2]=(bf16_t)v[2]; o[3]=(bf16_t)v[3];
    *(bf16x4*)&Xs[row*XS + co] = o;
  }
  __syncthreads();
  const int lane = tid & 63, wave = tid >> 6, lr = lane & 15, lk = lane >> 4;
  f32x4 acc[16];
  #pragma unroll
  for (int nt=0;nt<16;nt++) acc[nt] = (f32x4){0.f,0.f,0.f,0.f};
  #pragma unroll
  for (int kc=0;kc<8;kc++){
    bf16x8 a = *(const bf16x8*)&Xs[(wave*16 + lr)*XS + kc*32 + lk*8];
    #pragma unroll
    for (int nt=0;nt<16;nt++){
      bf16x8 b = *(const bf16x8*)&BT[(size_t)(nt*16 + lr)*256 + kc*32 + lk*8];
      acc[nt] = MFMA16(a,b,acc[nt]);
    }
  }
  #pragma unroll
  for (int nt=0;nt<16;nt++)
    #pragma unroll
    for (int r=0;r<4;r++)
      Cs[(wave*16 + lk*4 + r)*CS + nt*16 + lr] = (bf16_t)acc[nt][r];
  __syncthreads();
  #pragma unroll
  for (int it=0; it<8; ++it){
    int c = tid + it*256;
    int row = c >> 5, co = (c & 31)*8;
    *(bf16x8*)&wcat[(size_t)(rb+row)*768 + cb*256 + co] = *(const bf16x8*)&Cs[row*CS + co];
  }
}

// wcat[:, 512:768] = Wn1[:, 256:512] (bf16)
__global__ void wcat_copy_kernel(const float* __restrict__ Wn1, bf16_t* __restrict__ wcat){
  int idx = (blockIdx.x*256 + threadIdx.x)*4;   // 65536 elems
  int n = idx >> 8, k = idx & 255;
  f32x4 v = *(const f32x4*)(Wn1 + (size_t)n*512 + 256 + k);
  bf16x4 o; o[0]=(bf16_t)v[0]; o[1]=(bf16_t)v[1]; o[2]=(bf16_t)v[2]; o[3]=(bf16_t)v[3];
  *(bf16x4*)(wcat + (size_t)n*768 + 512 + k) = o;
}

// u[n] = sum_j Wn1[n,j]*bm2[j], w[n] = sum_j Wn1[n,j]*br2[j]  (j<256)
__global__ __launch_bounds__(256) void uw_kernel(const float* __restrict__ Wn1,
    const float* __restrict__ bm2, const float* __restrict__ br2,
    float* __restrict__ u, float* __restrict__ w){
  const int n = threadIdx.x;
  float su=0.f, sw=0.f;
  for (int j=0;j<256;j+=4){
    f32x4 wv = *(const f32x4*)(Wn1 + (size_t)n*512 + j);
    f32x4 bu = *(const f32x4*)(bm2 + j);
    f32x4 bw = *(const f32x4*)(br2 + j);
    #pragma unroll
    for (int q=0;q<4;q++){ su += wv[q]*bu[q]; sw += wv[q]*bw[q]; }
  }
  u[n]=su; w[n]=sw;
}

// ---------------- nsT: d-major, slot-permuted transpose of ns (bf16) ----------------
__global__ __launch_bounds__(256) void nst_kernel(const float* __restrict__ ns, bf16_t* __restrict__ nsT){
  constexpr int XS2 = 136;
  __shared__ bf16_t Xs[64*XS2];
  const int tid = threadIdx.x;
  const int nb = blockIdx.x*64;
  #pragma unroll
  for (int it=0; it<8; ++it){
    int c = tid + it*256;
    int rowl = c >> 5, co = (c & 31)*4;
    f32x4 v = *(const f32x4*)(ns + (size_t)(nb+rowl)*DD + co);
    bf16x4 o; o[0]=(bf16_t)v[0]; o[1]=(bf16_t)v[1]; o[2]=(bf16_t)v[2]; o[3]=(bf16_t)v[3];
    *(bf16x4*)&Xs[rowl*XS2 + co] = o;
  }
  __syncthreads();
  const int sb = nb >> 11;
  const int jb = nb & 2047;
  bf16_t* outp = nsT + (size_t)sb*DD*2048 + jb;
  #pragma unroll
  for (int it=0; it<4; ++it){
    int c = tid + it*256;
    int d = c >> 3, g8 = (c & 7)*8;
    bf16x8 o;
    #pragma unroll
    for (int k=0;k<8;k++){
      int s64 = g8 + k;
      int t32 = s64 >> 5, s = s64 & 31;
      int m = (s & 1) ? (16 + (s>>1)) : (s>>1);
      o[k] = Xs[(t32*32 + m)*XS2 + d];
    }
    *(bf16x8*)(outp + (size_t)d*2048 + g8) = o;
  }
}

// ---------------- cross-graph attention: no-max softmax, dbuf, conflict-free LDS ----------------
__global__ __launch_bounds__(256,2) void attn_kernel(
    const bf16_t* __restrict__ nsB, const bf16_t* __restrict__ nsT,
    const float* __restrict__ ns, bf16_t* __restrict__ attnB)
{
  constexpr int KS = 136;
  constexpr int VS = 40;
  constexpr int PS = 40;
  __shared__ bf16_t Ks[2][32*KS];
  __shared__ bf16_t Vt[2][128*VS];
  __shared__ bf16_t Ps[64*PS];
  const int tid = threadIdx.x;
  const int lane = tid & 63, wave = tid >> 6, lr = lane & 15, lk = lane >> 4;
  const int bx = blockIdx.x;
  const int qt = bx & 31, side = (bx>>5)&1, p = bx>>6;
  const size_t qbase = (size_t)p*4096 + (size_t)side*2048 + (size_t)qt*64;
  const int sbkv = p*2 + (side^1);
  const bf16_t* Kv = nsB + ((size_t)p*4096 + (size_t)(side^1)*2048)*DD;
  const bf16_t* Vp = nsT + (size_t)sbkv*DD*2048;

  bf16x8 qf[4];
  {
    const bf16_t* qrow = nsB + (qbase + wave*16 + lr)*DD;
    #pragma unroll
    for (int kc=0;kc<4;kc++) qf[kc] = *(const bf16x8*)(qrow + kc*32 + lk*8);
  }
  float ls[4] = {0.f,0.f,0.f,0.f};
  f32x4 acco[8];
  #pragma unroll
  for (int nt=0;nt<8;nt++) acco[nt]=(f32x4){0.f,0.f,0.f,0.f};

  const int krow0 = tid>>4,        kcol = (tid&15)*8;
  const int vd0   = tid>>2,        vsl  = (tid&3)*8;
  bf16x8 kreg0, kreg1, vreg0, vreg1;

  auto load_tile = [&](int t){
    const bf16_t* kp = Kv + (size_t)t*32*DD;
    kreg0 = *(const bf16x8*)(kp + (size_t)krow0*DD + kcol);
    kreg1 = *(const bf16x8*)(kp + (size_t)(krow0+16)*DD + kcol);
    const bf16_t* vp = Vp + t*32;
    vreg0 = *(const bf16x8*)(vp + (size_t)vd0*2048 + vsl);
    vreg1 = *(const bf16x8*)(vp + (size_t)(vd0+64)*2048 + vsl);
  };
  auto store_tile = [&](int b){
    *(bf16x8*)&Ks[b][krow0*KS + kcol]      = kreg0;
    *(bf16x8*)&Ks[b][(krow0+16)*KS + kcol] = kreg1;
    *(bf16x8*)&Vt[b][vd0*VS + vsl]         = vreg0;
    *(bf16x8*)&Vt[b][(vd0+64)*VS + vsl]    = vreg1;
  };

  load_tile(0);
  store_tile(0);
  load_tile(1);
  __syncthreads();
  int cur = 0;
  for (int t=0; t<64; ++t){
    if (t+1 < 64){
      store_tile(cur^1);
      if (t+2 < 64) load_tile(t+2);
    }
    f32x4 s0 = (f32x4){0.f,0.f,0.f,0.f}, s1 = (f32x4){0.f,0.f,0.f,0.f};
    #pragma unroll
    for (int kc=0;kc<4;kc++){
      bf16x8 b0 = *(const bf16x8*)&Ks[cur][lr*KS      + kc*32 + lk*8];
      bf16x8 b1 = *(const bf16x8*)&Ks[cur][(16+lr)*KS + kc*32 + lk*8];
      s0 = MFMA16(qf[kc], b0, s0);
      s1 = MFMA16(qf[kc], b1, s1);
    }
    #pragma unroll
    for (int r=0;r<4;r++){
      float p0 = __expf(s0[r] - 40.f);
      float p1 = __expf(s1[r] - 40.f);
      ls[r] += p0 + p1;
      union { bf16_t h[2]; unsigned u; } pk;
      pk.h[0] = (bf16_t)p0; pk.h[1] = (bf16_t)p1;
      *(unsigned*)&Ps[(wave*16 + lk*4 + r)*PS + 2*lr] = pk.u;
    }
    asm volatile("s_waitcnt lgkmcnt(0)" ::: "memory");
    __builtin_amdgcn_sched_barrier(0);
    bf16x8 pa = *(const bf16x8*)&Ps[(wave*16 + lr)*PS + lk*8];
    #pragma unroll
    for (int nt=0;nt<8;nt++){
      bf16x8 vb = *(const bf16x8*)&Vt[cur][(nt*16+lr)*VS + lk*8];
      acco[nt] = MFMA16(pa, vb, acco[nt]);
    }
    __syncthreads();
    cur ^= 1;
  }
  #pragma unroll
  for (int r=0;r<4;r++){
    float v = ls[r];
    v += __shfl_xor(v,1); v += __shfl_xor(v,2);
    v += __shfl_xor(v,4); v += __shfl_xor(v,8);
    ls[r] = 1.f/v;
  }
  #pragma unroll
  for (int nt=0;nt<8;nt++){
    const int col = nt*16 + lr;
    #pragma unroll
    for (int r=0;r<4;r++){
      const size_t row = qbase + wave*16 + lk*4 + r;
      attnB[row*DD + col] = (bf16_t)(ns[row*DD + col] - acco[nt][r]*ls[r]);
    }
  }
}

// ---------------- fused node MLP (agg_gemm folded in) + residual ----------------
// layer1: K=768 over [aggh_f|aggh_r|attnB|nsB] with Wcat; + bn1 + dt*u + df*w; relu
// layer2: K=256 -> 128 with Wn2; + bn2 + ns residual
__global__ __launch_bounds__(256,2) void node_mlp_kernel(
    const bf16_t* __restrict__ agghf, const bf16_t* __restrict__ agghr,
    const bf16_t* __restrict__ attnB, const bf16_t* __restrict__ nsB,
    const float* __restrict__ ns,
    const bf16_t* __restrict__ wcat, const float* __restrict__ bn1,
    const float* __restrict__ uvec, const float* __restrict__ wvec,
    const int* __restrict__ start_to, const int* __restrict__ start_from,
    const bf16_t* __restrict__ Wn2b, const float* __restrict__ bn2,
    float* __restrict__ out)
{
  __shared__ __align__(16) bf16_t As[32*768];   // 48KB; Hs overlays after layer1
  bf16_t* Hs = As;
  const int tid = threadIdx.x;
  const int lane = tid & 63, wave = tid >> 6, lr = lane & 15, lk = lane >> 4;
  const int rb = blockIdx.x*32;

  // reg-staged A-tile: 32 rows x 1536B, XOR-swizzled LDS writes (conflict-free reads)
  bf16x8 stg[12];
  int dsta[12];
  #pragma unroll
  for (int it=0; it<12; ++it){
    const int db = it*4096 + tid*16;
    const int row = db / 1536;
    const int within = db - row*1536;
    const size_t node = (size_t)(rb + row);
    const char* s0 = (const char*)agghf + (node<<9) + within;
    const char* s1 = (const char*)agghr + (node<<9) + (within-512);
    const char* s2 = (const char*)attnB + (node<<8) + (within-1024);
    const char* s3 = (const char*)nsB   + (node<<8) + (within-1280);
    const char* src = within < 512 ? s0 : (within < 1024 ? s1 : (within < 1280 ? s2 : s3));
    stg[it] = *(const bf16x8*)src;
    dsta[it] = row*1536 + (within ^ ((row & 7) << 4));
  }
  #pragma unroll
  for (int it=0; it<12; ++it)
    *(bf16x8*)((char*)As + dsta[it]) = stg[it];
  __syncthreads();

  // ---- layer 1: per wave 16 rows x 128 cols, K=768 ----
  const int colbase = (wave >> 1) * 128;
  const int arow = (wave & 1)*16 + lr;
  const unsigned abase = (unsigned)arow * 1536u;
  const unsigned asw = ((unsigned)(arow & 7)) << 4;
  f32x4 acc[8];
  #pragma unroll
  for (int nt=0;nt<8;nt++) acc[nt] = (f32x4){0.f,0.f,0.f,0.f};
  #pragma unroll
  for (int kc=0; kc<24; ++kc){
    const unsigned y = (unsigned)(kc*64 + lk*16);
    bf16x8 a = *(const bf16x8*)((const char*)As + abase + (y ^ asw));
    #pragma unroll
    for (int nt=0;nt<8;nt++){
      bf16x8 b = *(const bf16x8*)&wcat[(size_t)(colbase + nt*16 + lr)*768 + kc*32 + lk*8];
      acc[nt] = MFMA16(a,b,acc[nt]);
    }
  }
  __syncthreads();   // all A reads done before Hs overlay

  const int r0 = rb + (wave&1)*16 + lk*4;
  float dt[4], df[4];
  #pragma unroll
  for (int r=0;r<4;r++){
    dt[r] = (float)(start_to[r0+r+1]   - start_to[r0+r]);
    df[r] = (float)(start_from[r0+r+1] - start_from[r0+r]);
  }
  #pragma unroll
  for (int nt=0;nt<8;nt++){
    const int col = colbase + nt*16 + lr;
    const float bias = bn1[col];
    const float uu = uvec[col], ww = wvec[col];
    #pragma unroll
    for (int r=0;r<4;r++){
      float v = acc[nt][r] + bias + dt[r]*uu + df[r]*ww;
      v = v > 0.f ? v : 0.f;
      Hs[((wave&1)*16 + lk*4 + r)*264 + col] = (bf16_t)v;
    }
  }
  __syncthreads();

  // ---- layer 2: per wave 16 rows x 64 cols, K=256 ----
  f32x4 acc2[4];
  #pragma unroll
  for (int nt=0;nt<4;nt++) acc2[nt] = (f32x4){0.f,0.f,0.f,0.f};
  #pragma unroll
  for (int kc=0;kc<8;kc++){
    bf16x8 a = *(const bf16x8*)&Hs[((wave&1)*16 + lr)*264 + kc*32 + lk*8];
    #pragma unroll
    for (int nt=0;nt<4;nt++){
      bf16x8 b = *(const bf16x8*)&Wn2b[(size_t)((wave>>1)*64 + nt*16 + lr)*256 + kc*32 + lk*8];
      acc2[nt] = MFMA16(a,b,acc2[nt]);
    }
  }
  #pragma unroll
  for (int nt=0;nt<4;nt++){
    const int col = (wave>>1)*64 + nt*16 + lr;
    const float bias = bn2[col];
    #pragma unroll
    for (int r=0;r<4;r++){
      const size_t rr = (size_t)(r0 + r);
      out[rr*DD + col] = acc2[nt][r] + bias + ns[rr*DD + col];
    }
  }
}

extern "C" void kernel_launch(void* const* d_in, const int* in_sizes, int n_in,
                              void* d_out, int out_size, void* d_ws, size_t ws_size,
                              hipStream_t stream) {
  const float* ns  = (const float*)d_in[0];
  const float* ef  = (const float*)d_in[1];
  const int* from_idx = (const int*)d_in[2];
  const int* to_idx   = (const int*)d_in[3];
  const float* Wm1 = (const float*)d_in[6];  const float* bm1 = (const float*)d_in[7];
  const float* Wm2 = (const float*)d_in[8];  const float* bm2 = (const float*)d_in[9];
  const float* Wr1 = (const float*)d_in[10]; const float* br1 = (const float*)d_in[11];
  const float* Wr2 = (const float*)d_in[12]; const float* br2 = (const float*)d_in[13];
  const float* Wn1 = (const float*)d_in[14]; const float* bn1 = (const float*)d_in[15];
  const float* Wn2 = (const float*)d_in[16]; const float* bn2 = (const float*)d_in[17];

  char* ws = (char*)d_ws;
  bf16_t* Ec     = (bf16_t*)(ws);                      // 134,217,728 (phase 1)
  bf16_t* P1t    = (bf16_t*)(ws + 134217728);
  bf16_t* P2t    = (bf16_t*)(ws + 150994944);
  bf16_t* aggh_f = (bf16_t*)(ws + 167772160);
  bf16_t* aggh_r = (bf16_t*)(ws + 184549376);
  bf16_t* wpb  = (bf16_t*)(ws + 201326592);
  bf16_t* wcb  = (bf16_t*)(ws + 201588736);
  bf16_t* wn2b = (bf16_t*)(ws + 201654272);
  int* cur_to     = (int*)(ws + 202244096);
  int* cur_from   = (int*)(ws + 202375168);
  int* start_to   = (int*)(ws + 202506240);
  int* start_from = (int*)(ws + 202637320);
  int* eid_to     = (int*)(ws + 202768400);
  int* eid_from   = (int*)(ws + 203816976);
  // phase-2 overlays inside dead Ec region:
  bf16_t* attnB = (bf16_t*)(ws);                       // 8 MB
  bf16_t* nsB   = (bf16_t*)(ws + 33554432);            // 8 MB
  bf16_t* nsT   = (bf16_t*)(ws + 41943040);            // 8 MB
  bf16_t* wm2T  = (bf16_t*)(ws + 50331648);            // 128 KB
  bf16_t* wr2T  = (bf16_t*)(ws + 50462720);            // 128 KB
  bf16_t* wcat  = (bf16_t*)(ws + 50593792);            // 384 KB
  float*  uvec  = (float*) (ws + 50987008);            // 1 KB
  float*  wvec  = (float*) (ws + 50988032);            // 1 KB

  hipMemsetAsync(cur_to, 0, 2*NNODES*sizeof(int), stream);

  cvt_wp_kernel<<<128, 256, 0, stream>>>(Wm1, Wr1, wpb);
  cvt_wc_kernel<<<32, 256, 0, stream>>>(Wm1, Wr1, wcb);
  cvt_kernel<<<32, 256, 0, stream>>>(Wn2, wn2b, 128*256);

  hist_kernel<<<NEDGES/256, 256, 0, stream>>>(to_idx, from_idx, cur_to, cur_from);
  scan_kernel<<<1, 1024, 0, stream>>>(cur_to, start_to);
  scan_kernel<<<1, 1024, 0, stream>>>(cur_from, start_from);
  place_kernel<<<NEDGES/256, 256, 0, stream>>>(to_idx, from_idx, cur_to, cur_from, eid_to, eid_from);

  // forward: h = relu(Pa[from] + Pb[to] + Ec + bm1), aggregate at to
  proj_kernel<<<dim3(NNODES/64, 2), 256, 0, stream>>>(ns, wpb, P1t, P2t);
  ec_kernel<<<NEDGES/64, 256, 0, stream>>>(ef, wcb, eid_to, Ec);
  gather_agg_kernel<<<NNODES/4, 256, 0, stream>>>(Ec, P1t, P2t, bm1,
      start_to, eid_to, from_idx, aggh_f);

  // reverse: aggregate at from
  proj_kernel<<<dim3(NNODES/64, 2), 256, 0, stream>>>(ns, wpb + 512*128, P1t, P2t);
  ec_kernel<<<NEDGES/64, 256, 0, stream>>>(ef, wcb + 256*64, eid_from, Ec);
  gather_agg_kernel<<<NNODES/4, 256, 0, stream>>>(Ec, P1t, P2t, br1,
      start_from, eid_from, to_idx, aggh_r);

  // phase 2 prep (Ec region now dead)
  cvt_kernel<<<4096, 256, 0, stream>>>(ns, nsB, NNODES*DD);
  nst_kernel<<<NNODES/64, 256, 0, stream>>>(ns, nsT);
  w2t_kernel<<<32, 256, 0, stream>>>(Wm2, Wr2, wm2T, wr2T);
  wcat_gemm_kernel<<<dim3(4,2), 256, 0, stream>>>(Wn1, wm2T, wr2T, wcat);
  wcat_copy_kernel<<<64, 256, 0, stream>>>(Wn1, wcat);
  uw_kernel<<<1, 256, 0, stream>>>(Wn1, bm2, br2, uvec, wvec);

  attn_kernel<<<512, 256, 0, stream>>>(nsB, nsT, ns, attnB);

  node_mlp_kernel<<<NNODES/32, 256, 0, stream>>>(aggh_f, aggh_r, attnB, nsB, ns,
      wcat, bn1, uvec, wvec, start_to, start_from, wn2b, bn2, (float*)d_out);
}

// Round 9
// 577.625 us; speedup vs baseline: 2.6486x; 1.1186x over previous
//
#include <hip/hip_runtime.h>

// NOTE: blockDim 256 = FOUR wave64s. wave = tid>>6 ∈ {0,1,2,3}.
//   node_mlp decomposition: wave&1 = row-group (2x16 rows), wave>>1 = col-group (2 groups).
//   Layer1: 2 col-groups x acc[8] tiles = 256 cols. Layer2: 2 col-groups x acc2[4] = 128 cols.

typedef __bf16 bf16_t;
typedef __bf16 bf16x8 __attribute__((ext_vector_type(8)));
typedef __bf16 bf16x4 __attribute__((ext_vector_type(4)));
typedef float  f32x4  __attribute__((ext_vector_type(4)));

#define MFMA16(a,b,c) __builtin_amdgcn_mfma_f32_16x16x32_bf16((a),(b),(c),0,0,0)

constexpr int NNODES = 32768;
constexpr int NEDGES = 262144;
constexpr int DD = 128;
constexpr int HH = 256;

__device__ __forceinline__ bf16x8 cvt8(f32x4 a, f32x4 b){
  bf16x8 r;
  r[0]=(bf16_t)a[0]; r[1]=(bf16_t)a[1]; r[2]=(bf16_t)a[2]; r[3]=(bf16_t)a[3];
  r[4]=(bf16_t)b[0]; r[5]=(bf16_t)b[1]; r[6]=(bf16_t)b[2]; r[7]=(bf16_t)b[3];
  return r;
}

__global__ void cvt_kernel(const float* __restrict__ in, bf16_t* __restrict__ out, int n){
  int i = (blockIdx.x*256 + threadIdx.x)*4;
  if (i < n){
    f32x4 v = *(const f32x4*)(in + i);
    bf16x4 o; o[0]=(bf16_t)v[0]; o[1]=(bf16_t)v[1]; o[2]=(bf16_t)v[2]; o[3]=(bf16_t)v[3];
    *(bf16x4*)(out + i) = o;
  }
}

// wpb[1024][128]: rows 0..255 = Wm1[:,0:128], 256..511 = Wm1[:,128:256],
//                 512..767 = Wr1[:,0:128], 768..1023 = Wr1[:,128:256]   (row-major, 646-proven)
__global__ void cvt_wp_kernel(const float* __restrict__ Wm1, const float* __restrict__ Wr1,
                              bf16_t* __restrict__ wp){
  int idx = (blockIdx.x*256 + threadIdx.x)*4;
  int n = idx >> 7, k = idx & 127;
  const float* W = (n < 512) ? Wm1 : Wr1;
  int row = n & 255;
  int colbase = ((n >> 8) & 1) * 128;
  f32x4 v = *(const f32x4*)(W + (size_t)row*320 + colbase + k);
  bf16x4 o; o[0]=(bf16_t)v[0]; o[1]=(bf16_t)v[1]; o[2]=(bf16_t)v[2]; o[3]=(bf16_t)v[3];
  *(bf16x4*)(wp + idx) = o;
}

// wcb[512][64]: rows 0..255 = Wm1[:,256:320], 256..511 = Wr1[:,256:320]   (row-major, 646-proven)
__global__ void cvt_wc_kernel(const float* __restrict__ Wm1, const float* __restrict__ Wr1,
                              bf16_t* __restrict__ wc){
  int idx = (blockIdx.x*256 + threadIdx.x)*4;
  int n = idx >> 6, k = idx & 63;
  const float* W = (n < 256) ? Wm1 : Wr1;
  int row = n & 255;
  f32x4 v = *(const f32x4*)(W + (size_t)row*320 + 256 + k);
  bf16x4 o; o[0]=(bf16_t)v[0]; o[1]=(bf16_t)v[1]; o[2]=(bf16_t)v[2]; o[3]=(bf16_t)v[3];
  *(bf16x4*)(wc + idx) = o;
}

// wn2b in MFMA B-tile order: dst[((kc*8+nt)*64+lane)*8+j] = Wn2[nt*16+(lane&15)][kc*32+(lane>>4)*8+j]
__global__ void pack_wn2_kernel(const float* __restrict__ Wn2, bf16_t* __restrict__ out){
  int g = blockIdx.x*256 + threadIdx.x;    // 4096 groups
  int tile = g >> 6, lane = g & 63;
  int kc = tile >> 3, nt = tile & 7;
  int lr = lane & 15, lk = lane >> 4;
  int row = nt*16 + lr;
  int col = kc*32 + lk*8;
  f32x4 v0 = *(const f32x4*)(Wn2 + (size_t)row*256 + col);
  f32x4 v1 = *(const f32x4*)(Wn2 + (size_t)row*256 + col + 4);
  *(bf16x8*)(out + (size_t)g*8) = cvt8(v0,v1);
}

// ---------------- CSR build ----------------
__global__ void hist_kernel(const int* __restrict__ to_idx, const int* __restrict__ from_idx,
                            int* __restrict__ cnt_to, int* __restrict__ cnt_from){
  int e = blockIdx.x*256 + threadIdx.x;
  if (e < NEDGES){
    atomicAdd(&cnt_to[to_idx[e]], 1);
    atomicAdd(&cnt_from[from_idx[e]], 1);
  }
}

__global__ void scan_kernel(int* __restrict__ cnt, int* __restrict__ start){
  __shared__ int sums[1024];
  const int t = threadIdx.x;
  int local[32]; int s = 0;
  #pragma unroll
  for (int j=0;j<32;j++){ local[j] = cnt[t*32+j]; s += local[j]; }
  sums[t] = s; __syncthreads();
  #pragma unroll
  for (int d=1; d<1024; d<<=1){
    int v = (t>=d) ? sums[t-d] : 0;
    __syncthreads();
    sums[t] += v;
    __syncthreads();
  }
  int off = sums[t] - s;
  #pragma unroll
  for (int j=0;j<32;j++){
    start[t*32+j] = off;
    cnt[t*32+j]   = off;
    off += local[j];
  }
  if (t == 1023) start[32768] = sums[1023];
}

__global__ void place_kernel(const int* __restrict__ to_idx, const int* __restrict__ from_idx,
                             int* __restrict__ cur_to, int* __restrict__ cur_from,
                             int* __restrict__ eid_to, int* __restrict__ eid_from){
  int e = blockIdx.x*256 + threadIdx.x;
  if (e < NEDGES){
    int p = atomicAdd(&cur_to[to_idx[e]], 1);
    eid_to[p] = e;
    int q = atomicAdd(&cur_from[from_idx[e]], 1);
    eid_from[q] = e;
  }
}

// ---------------- node projections: P = ns @ Wblock^T (K=128) ----------------
__global__ __launch_bounds__(256,3) void proj_kernel(
    const float* __restrict__ ns, const bf16_t* __restrict__ Wp,
    bf16_t* __restrict__ P1, bf16_t* __restrict__ P2)
{
  constexpr int XS = 136;
  constexpr int CS = 264;
  __shared__ bf16_t Xs[64*XS];
  __shared__ bf16_t Cs[64*CS];
  const int tid = threadIdx.x;
  const int rb = blockIdx.x*64;
  const int cb = blockIdx.y;
  #pragma unroll
  for (int it=0; it<8; ++it){
    int c = tid + it*256;
    int row = c >> 5, co = (c & 31)*4;
    f32x4 v = *(const f32x4*)(ns + (size_t)(rb+row)*DD + co);
    bf16x4 o; o[0]=(bf16_t)v[0]; o[1]=(bf16_t)v[1]; o[2]=(bf16_t)v[2]; o[3]=(bf16_t)v[3];
    *(bf16x4*)&Xs[row*XS + co] = o;
  }
  __syncthreads();
  const int lane = tid & 63, wave = tid >> 6, lr = lane & 15, lk = lane >> 4;
  const bf16_t* Wb = Wp + (size_t)cb*256*128;
  f32x4 acc[16];
  #pragma unroll
  for (int nt=0;nt<16;nt++) acc[nt] = (f32x4){0.f,0.f,0.f,0.f};
  #pragma unroll
  for (int kc=0;kc<4;kc++){
    bf16x8 a = *(const bf16x8*)&Xs[(wave*16 + lr)*XS + kc*32 + lk*8];
    #pragma unroll
    for (int nt=0;nt<16;nt++){
      bf16x8 b = *(const bf16x8*)&Wb[(size_t)(nt*16 + lr)*128 + kc*32 + lk*8];
      acc[nt] = MFMA16(a,b,acc[nt]);
    }
  }
  #pragma unroll
  for (int nt=0;nt<16;nt++)
    #pragma unroll
    for (int r=0;r<4;r++)
      Cs[(wave*16 + lk*4 + r)*CS + nt*16 + lr] = (bf16_t)acc[nt][r];
  __syncthreads();
  bf16_t* P = cb ? P2 : P1;
  #pragma unroll
  for (int it=0; it<8; ++it){
    int c = tid + it*256;
    int row = c >> 5, co = (c & 31)*8;
    *(bf16x8*)&P[(size_t)(rb+row)*HH + co] = *(const bf16x8*)&Cs[row*CS + co];
  }
}

// ---------------- edge projection in CSR order: Ec[i] = ef[eid[i]] @ Wc^T ----------------
__global__ __launch_bounds__(256,3) void ec_kernel(
    const float* __restrict__ ef, const bf16_t* __restrict__ Wc,
    const int* __restrict__ eid, bf16_t* __restrict__ Ec)
{
  constexpr int XS = 72;
  constexpr int CS = 264;
  __shared__ bf16_t Xs[64*XS];
  __shared__ bf16_t Cs[64*CS];
  __shared__ int es[64];
  const int tid = threadIdx.x;
  const int rb = blockIdx.x*64;
  if (tid < 64) es[tid] = eid[rb + tid];
  __syncthreads();
  {
    const int row = tid>>2, part = tid&3;
    const float* s2 = ef + (size_t)es[row]*64 + part*16;
    #pragma unroll
    for (int j=0;j<4;j++){
      f32x4 v = *(const f32x4*)(s2 + j*4);
      bf16x4 o; o[0]=(bf16_t)v[0]; o[1]=(bf16_t)v[1]; o[2]=(bf16_t)v[2]; o[3]=(bf16_t)v[3];
      *(bf16x4*)&Xs[row*XS + part*16 + j*4] = o;
    }
  }
  __syncthreads();
  const int lane = tid & 63, wave = tid >> 6, lr = lane & 15, lk = lane >> 4;
  f32x4 acc[16];
  #pragma unroll
  for (int nt=0;nt<16;nt++) acc[nt] = (f32x4){0.f,0.f,0.f,0.f};
  #pragma unroll
  for (int kc=0;kc<2;kc++){
    bf16x8 a = *(const bf16x8*)&Xs[(wave*16 + lr)*XS + kc*32 + lk*8];
    #pragma unroll
    for (int nt=0;nt<16;nt++){
      bf16x8 b = *(const bf16x8*)&Wc[(size_t)(nt*16 + lr)*64 + kc*32 + lk*8];
      acc[nt] = MFMA16(a,b,acc[nt]);
    }
  }
  #pragma unroll
  for (int nt=0;nt<16;nt++)
    #pragma unroll
    for (int r=0;r<4;r++)
      Cs[(wave*16 + lk*4 + r)*CS + nt*16 + lr] = (bf16_t)acc[nt][r];
  __syncthreads();
  #pragma unroll
  for (int it=0; it<8; ++it){
    int c = tid + it*256;
    int row = c >> 5, co = (c & 31)*8;
    *(bf16x8*)&Ec[(size_t)(rb+row)*HH + co] = *(const bf16x8*)&Cs[row*CS + co];
  }
}

// ---------------- fused combine + aggregate; Ec streamed in CSR order ----------------
__global__ __launch_bounds__(256) void gather_agg_kernel(
    const bf16_t* __restrict__ Ec, const bf16_t* __restrict__ P1,
    const bf16_t* __restrict__ P2, const float* __restrict__ b1,
    const int* __restrict__ start, const int* __restrict__ eid,
    const int* __restrict__ oth, bf16_t* __restrict__ aggh)
{
  const int wave = threadIdx.x >> 6;
  const int lane = threadIdx.x & 63;
  const int half = lane >> 5;
  const int l32  = lane & 31;
  const int c0 = l32*8;
  const int v = blockIdx.x*4 + wave;
  float base[8];
  {
    bf16x8 p2 = *(const bf16x8*)&P2[(size_t)v*HH + c0];
    f32x4 b0 = *(const f32x4*)(b1 + c0);
    f32x4 b4 = *(const f32x4*)(b1 + c0 + 4);
    #pragma unroll
    for (int j=0;j<4;j++){ base[j] = (float)p2[j] + b0[j]; base[4+j] = (float)p2[4+j] + b4[j]; }
  }
  float acc[8] = {0.f,0.f,0.f,0.f,0.f,0.f,0.f,0.f};
  const int s = start[v], e_end = start[v+1];
  for (int i = s + half; i < e_end; i += 2){
    const int eg = eid[i];
    const int o  = oth[eg];
    bf16x8 ec = *(const bf16x8*)&Ec[(size_t)i*HH + c0];
    bf16x8 p1 = *(const bf16x8*)&P1[(size_t)o*HH + c0];
    #pragma unroll
    for (int j=0;j<8;j++){
      float x = base[j] + (float)ec[j] + (float)p1[j];
      acc[j] += fmaxf(x, 0.f);
    }
  }
  #pragma unroll
  for (int j=0;j<8;j++) acc[j] += __shfl(acc[j], lane ^ 32);
  if (half == 0){
    bf16x8 o8;
    #pragma unroll
    for (int j=0;j<8;j++) o8[j] = (bf16_t)acc[j];
    *(bf16x8*)&aggh[(size_t)v*HH + c0] = o8;
  }
}

// ---------------- weight prep for fused node MLP ----------------
__global__ __launch_bounds__(256) void w2t_kernel(const float* __restrict__ Wm2, const float* __restrict__ Wr2,
                                                  bf16_t* __restrict__ wm2T, bf16_t* __restrict__ wr2T){
  __shared__ bf16_t t[64][72];
  const int bi = (blockIdx.x & 3)*64;
  const int bj = ((blockIdx.x>>2) & 3)*64;
  const int m  = blockIdx.x >> 4;
  const float* W = m ? Wr2 : Wm2;
  bf16_t* WT = m ? wr2T : wm2T;
  const int tid = threadIdx.x;
  #pragma unroll
  for (int it=0; it<16; ++it){
    int c = tid + it*256;
    int r = c >> 6, co = c & 63;
    t[r][co] = (bf16_t)W[(size_t)(bi+r)*256 + bj + co];
  }
  __syncthreads();
  #pragma unroll
  for (int it=0; it<16; ++it){
    int c = tid + it*256;
    int r = c >> 6, co = c & 63;
    WT[(size_t)(bj+r)*256 + bi + co] = t[co][r];
  }
}

// wcat in MFMA B-tile order over N=256 (16 n-tiles), K=768 (24 k-chunks):
// wcat[((kc*16+nt)*64+lane)*8+j] = Weff[nt*16+(lane&15)][kc*32+(lane>>4)*8+j]
// this kernel fills kc 0..15 (Weff k-cols 0..511 = Wn1a@Wm2 | Wn1a@Wr2)
__global__ __launch_bounds__(256,2) void wcat_gemm_kernel(
    const float* __restrict__ Wn1, const bf16_t* __restrict__ wm2T, const bf16_t* __restrict__ wr2T,
    bf16_t* __restrict__ wcat)
{
  constexpr int XS = 264, CS = 264;
  __shared__ bf16_t Xs[64*XS];
  __shared__ bf16_t Cs[64*CS];
  const int tid = threadIdx.x;
  const int rb = blockIdx.x*64;      // N rows rb..rb+63
  const int cb = blockIdx.y;         // k-half: 0 -> Wm2, 1 -> Wr2
  const bf16_t* BT = cb ? wr2T : wm2T;
  #pragma unroll
  for (int it=0; it<16; ++it){
    int c = tid + it*256;
    int row = c >> 6, co = (c & 63)*4;
    f32x4 v = *(const f32x4*)(Wn1 + (size_t)(rb+row)*512 + co);
    bf16x4 o; o[0]=(bf16_t)v[0]; o[1]=(bf16_t)v[1]; o[2]=(bf16_t)v[2]; o[3]=(bf16_t)v[3];
    *(bf16x4*)&Xs[row*XS + co] = o;
  }
  __syncthreads();
  const int lane = tid & 63, wave = tid >> 6, lr = lane & 15, lk = lane >> 4;
  f32x4 acc[16];
  #pragma unroll
  for (int nt=0;nt<16;nt++) acc[nt] = (f32x4){0.f,0.f,0.f,0.f};
  #pragma unroll
  for (int kc=0;kc<8;kc++){
    bf16x8 a = *(const bf16x8*)&Xs[(wave*16 + lr)*XS + kc*32 + lk*8];
    #pragma unroll
    for (int nt=0;nt<16;nt++){
      bf16x8 b = *(const bf16x8*)&BT[(size_t)(nt*16 + lr)*256 + kc*32 + lk*8];
      acc[nt] = MFMA16(a,b,acc[nt]);
    }
  }
  #pragma unroll
  for (int nt=0;nt<16;nt++)
    #pragma unroll
    for (int r=0;r<4;r++)
      Cs[(wave*16 + lk*4 + r)*CS + nt*16 + lr] = (bf16_t)acc[nt][r];
  __syncthreads();
  // tile-order write: n_tile = rb/16 + nt_l, kc_glob = cb*8 + kc_l
  const int nt_base = rb >> 4;
  #pragma unroll
  for (int it=0; it<8; ++it){
    int g = tid + it*256;                 // 2048 groups: 8 kc_l x 4 nt_l x 64 lanes
    int tile = g >> 6, lane2 = g & 63;
    int kc_l = tile >> 2, nt_l = tile & 3;
    int lr2 = lane2 & 15, lk2 = lane2 >> 4;
    bf16x8 v = *(const bf16x8*)&Cs[(nt_l*16 + lr2)*CS + kc_l*32 + lk2*8];
    *(bf16x8*)&wcat[(size_t)(((cb*8 + kc_l)*16 + nt_base + nt_l)*64 + lane2)*8] = v;
  }
}

// wcat kc 16..23 (Weff k 512..767) = Wn1[:,256:512], tile order. 8192 groups.
__global__ void wcat_copy_kernel(const float* __restrict__ Wn1, bf16_t* __restrict__ wcat){
  int g = blockIdx.x*256 + threadIdx.x;
  int tile = g >> 6, lane = g & 63;
  int kc = tile >> 4, nt = tile & 15;       // kc 0..7, nt 0..15
  int lr = lane & 15, lk = lane >> 4;
  int row = nt*16 + lr;
  int col = 256 + kc*32 + lk*8;
  f32x4 v0 = *(const f32x4*)(Wn1 + (size_t)row*512 + col);
  f32x4 v1 = *(const f32x4*)(Wn1 + (size_t)row*512 + col + 4);
  *(bf16x8*)&wcat[(size_t)(((16 + kc)*16 + nt)*64 + lane)*8] = cvt8(v0,v1);
}

// u[n] = sum_j Wn1[n,j]*bm2[j], w[n] = sum_j Wn1[n,j]*br2[j]  (j<256)
__global__ __launch_bounds__(256) void uw_kernel(const float* __restrict__ Wn1,
    const float* __restrict__ bm2, const float* __restrict__ br2,
    float* __restrict__ u, float* __restrict__ w){
  const int n = threadIdx.x;
  float su=0.f, sw=0.f;
  for (int j=0;j<256;j+=4){
    f32x4 wv = *(const f32x4*)(Wn1 + (size_t)n*512 + j);
    f32x4 bu = *(const f32x4*)(bm2 + j);
    f32x4 bw = *(const f32x4*)(br2 + j);
    #pragma unroll
    for (int q=0;q<4;q++){ su += wv[q]*bu[q]; sw += wv[q]*bw[q]; }
  }
  u[n]=su; w[n]=sw;
}

// ---------------- nsT: d-major, slot-permuted transpose of ns (bf16) ----------------
__global__ __launch_bounds__(256) void nst_kernel(const float* __restrict__ ns, bf16_t* __restrict__ nsT){
  constexpr int XS2 = 136;
  __shared__ bf16_t Xs[64*XS2];
  const int tid = threadIdx.x;
  const int nb = blockIdx.x*64;
  #pragma unroll
  for (int it=0; it<8; ++it){
    int c = tid + it*256;
    int rowl = c >> 5, co = (c & 31)*4;
    f32x4 v = *(const f32x4*)(ns + (size_t)(nb+rowl)*DD + co);
    bf16x4 o; o[0]=(bf16_t)v[0]; o[1]=(bf16_t)v[1]; o[2]=(bf16_t)v[2]; o[3]=(bf16_t)v[3];
    *(bf16x4*)&Xs[rowl*XS2 + co] = o;
  }
  __syncthreads();
  const int sb = nb >> 11;
  const int jb = nb & 2047;
  bf16_t* outp = nsT + (size_t)sb*DD*2048 + jb;
  #pragma unroll
  for (int it=0; it<4; ++it){
    int c = tid + it*256;
    int d = c >> 3, g8 = (c & 7)*8;
    bf16x8 o;
    #pragma unroll
    for (int k=0;k<8;k++){
      int s64 = g8 + k;
      int t32 = s64 >> 5, s = s64 & 31;
      int m = (s & 1) ? (16 + (s>>1)) : (s>>1);
      o[k] = Xs[(t32*32 + m)*XS2 + d];
    }
    *(bf16x8*)(outp + (size_t)d*2048 + g8) = o;
  }
}

// ---------------- cross-graph attention: no-max softmax, dbuf, conflict-free LDS ----------------
__global__ __launch_bounds__(256,2) void attn_kernel(
    const bf16_t* __restrict__ nsB, const bf16_t* __restrict__ nsT,
    const float* __restrict__ ns, bf16_t* __restrict__ attnB)
{
  constexpr int KS = 136;
  constexpr int VS = 40;
  constexpr int PS = 40;
  __shared__ bf16_t Ks[2][32*KS];
  __shared__ bf16_t Vt[2][128*VS];
  __shared__ bf16_t Ps[64*PS];
  const int tid = threadIdx.x;
  const int lane = tid & 63, wave = tid >> 6, lr = lane & 15, lk = lane >> 4;
  const int bx = blockIdx.x;
  const int qt = bx & 31, side = (bx>>5)&1, p = bx>>6;
  const size_t qbase = (size_t)p*4096 + (size_t)side*2048 + (size_t)qt*64;
  const int sbkv = p*2 + (side^1);
  const bf16_t* Kv = nsB + ((size_t)p*4096 + (size_t)(side^1)*2048)*DD;
  const bf16_t* Vp = nsT + (size_t)sbkv*DD*2048;

  bf16x8 qf[4];
  {
    const bf16_t* qrow = nsB + (qbase + wave*16 + lr)*DD;
    #pragma unroll
    for (int kc=0;kc<4;kc++) qf[kc] = *(const bf16x8*)(qrow + kc*32 + lk*8);
  }
  float ls[4] = {0.f,0.f,0.f,0.f};
  f32x4 acco[8];
  #pragma unroll
  for (int nt=0;nt<8;nt++) acco[nt]=(f32x4){0.f,0.f,0.f,0.f};

  const int krow0 = tid>>4,        kcol = (tid&15)*8;
  const int vd0   = tid>>2,        vsl  = (tid&3)*8;
  bf16x8 kreg0, kreg1, vreg0, vreg1;

  auto load_tile = [&](int t){
    const bf16_t* kp = Kv + (size_t)t*32*DD;
    kreg0 = *(const bf16x8*)(kp + (size_t)krow0*DD + kcol);
    kreg1 = *(const bf16x8*)(kp + (size_t)(krow0+16)*DD + kcol);
    const bf16_t* vp = Vp + t*32;
    vreg0 = *(const bf16x8*)(vp + (size_t)vd0*2048 + vsl);
    vreg1 = *(const bf16x8*)(vp + (size_t)(vd0+64)*2048 + vsl);
  };
  auto store_tile = [&](int b){
    *(bf16x8*)&Ks[b][krow0*KS + kcol]      = kreg0;
    *(bf16x8*)&Ks[b][(krow0+16)*KS + kcol] = kreg1;
    *(bf16x8*)&Vt[b][vd0*VS + vsl]         = vreg0;
    *(bf16x8*)&Vt[b][(vd0+64)*VS + vsl]    = vreg1;
  };

  load_tile(0);
  store_tile(0);
  load_tile(1);
  __syncthreads();
  int cur = 0;
  for (int t=0; t<64; ++t){
    if (t+1 < 64){
      store_tile(cur^1);
      if (t+2 < 64) load_tile(t+2);
    }
    f32x4 s0 = (f32x4){0.f,0.f,0.f,0.f}, s1 = (f32x4){0.f,0.f,0.f,0.f};
    #pragma unroll
    for (int kc=0;kc<4;kc++){
      bf16x8 b0 = *(const bf16x8*)&Ks[cur][lr*KS      + kc*32 + lk*8];
      bf16x8 b1 = *(const bf16x8*)&Ks[cur][(16+lr)*KS + kc*32 + lk*8];
      s0 = MFMA16(qf[kc], b0, s0);
      s1 = MFMA16(qf[kc], b1, s1);
    }
    #pragma unroll
    for (int r=0;r<4;r++){
      float p0 = __expf(s0[r] - 40.f);
      float p1 = __expf(s1[r] - 40.f);
      ls[r] += p0 + p1;
      union { bf16_t h[2]; unsigned u; } pk;
      pk.h[0] = (bf16_t)p0; pk.h[1] = (bf16_t)p1;
      *(unsigned*)&Ps[(wave*16 + lk*4 + r)*PS + 2*lr] = pk.u;
    }
    asm volatile("s_waitcnt lgkmcnt(0)" ::: "memory");
    __builtin_amdgcn_sched_barrier(0);
    bf16x8 pa = *(const bf16x8*)&Ps[(wave*16 + lr)*PS + lk*8];
    #pragma unroll
    for (int nt=0;nt<8;nt++){
      bf16x8 vb = *(const bf16x8*)&Vt[cur][(nt*16+lr)*VS + lk*8];
      acco[nt] = MFMA16(pa, vb, acco[nt]);
    }
    __syncthreads();
    cur ^= 1;
  }
  #pragma unroll
  for (int r=0;r<4;r++){
    float v = ls[r];
    v += __shfl_xor(v,1); v += __shfl_xor(v,2);
    v += __shfl_xor(v,4); v += __shfl_xor(v,8);
    ls[r] = 1.f/v;
  }
  #pragma unroll
  for (int nt=0;nt<8;nt++){
    const int col = nt*16 + lr;
    #pragma unroll
    for (int r=0;r<4;r++){
      const size_t row = qbase + wave*16 + lk*4 + r;
      attnB[row*DD + col] = (bf16_t)(ns[row*DD + col] - acco[nt][r]*ls[r]);
    }
  }
}

// ---------------- fused node MLP (agg_gemm folded in) + residual ----------------
// 4 waves: wave&1 = row-group (16 rows), wave>>1 ∈ {0,1} = col-group.
// layer1: col-group covers 128 cols via acc[8]  -> 2x128 = 256 = N1. tile-ordered wcat.
// layer2: col-group covers 64 cols via acc2[4]  -> 2x64 = 128 = N2. tile-ordered wn2b.
__global__ __launch_bounds__(256,2) void node_mlp_kernel(
    const bf16_t* __restrict__ agghf, const bf16_t* __restrict__ agghr,
    const bf16_t* __restrict__ attnB, const bf16_t* __restrict__ nsB,
    const float* __restrict__ ns,
    const bf16_t* __restrict__ wcat, const float* __restrict__ bn1,
    const float* __restrict__ uvec, const float* __restrict__ wvec,
    const int* __restrict__ start_to, const int* __restrict__ start_from,
    const bf16_t* __restrict__ Wn2b, const float* __restrict__ bn2,
    float* __restrict__ out)
{
  __shared__ __align__(16) bf16_t As[32*768];   // 48KB; Hs overlays after layer1
  bf16_t* Hs = As;
  const int tid = threadIdx.x;
  const int lane = tid & 63, wave = tid >> 6, lr = lane & 15, lk = lane >> 4;
  const int rb = blockIdx.x*32;

  // reg-staged A-tile: 32 rows x 1536B, XOR-swizzled LDS writes (conflict-free reads)
  bf16x8 stg[12];
  int dsta[12];
  #pragma unroll
  for (int it=0; it<12; ++it){
    const int db = it*4096 + tid*16;
    const int row = db / 1536;
    const int within = db - row*1536;
    const size_t node = (size_t)(rb + row);
    const char* s0 = (const char*)agghf + (node<<9) + within;
    const char* s1 = (const char*)agghr + (node<<9) + (within-512);
    const char* s2 = (const char*)attnB + (node<<8) + (within-1024);
    const char* s3 = (const char*)nsB   + (node<<8) + (within-1280);
    const char* src = within < 512 ? s0 : (within < 1024 ? s1 : (within < 1280 ? s2 : s3));
    stg[it] = *(const bf16x8*)src;
    dsta[it] = row*1536 + (within ^ ((row & 7) << 4));
  }
  #pragma unroll
  for (int it=0; it<12; ++it)
    *(bf16x8*)((char*)As + dsta[it]) = stg[it];
  __syncthreads();

  // ---- layer 1: per wave 16 rows x 128 cols (8 n-tiles), K=768 ----
  const int cg = wave >> 1;                  // 0 or 1
  const int colbase = cg * 128;
  const int arow = (wave & 1)*16 + lr;
  const unsigned abase = (unsigned)arow * 1536u;
  const unsigned asw = ((unsigned)(arow & 7)) << 4;
  f32x4 acc[8];
  #pragma unroll
  for (int nt=0;nt<8;nt++) acc[nt] = (f32x4){0.f,0.f,0.f,0.f};
  #pragma unroll
  for (int kc=0; kc<24; ++kc){
    const unsigned y = (unsigned)(kc*64 + lk*16);
    bf16x8 a = *(const bf16x8*)((const char*)As + abase + (y ^ asw));
    #pragma unroll
    for (int nt=0;nt<8;nt++){
      bf16x8 b = *(const bf16x8*)&wcat[(size_t)((kc*16 + cg*8 + nt)*64 + lane)*8];
      acc[nt] = MFMA16(a,b,acc[nt]);
    }
  }
  __syncthreads();   // all A reads done before Hs overlay

  const int r0 = rb + (wave&1)*16 + lk*4;
  float dt[4], df[4];
  #pragma unroll
  for (int r=0;r<4;r++){
    dt[r] = (float)(start_to[r0+r+1]   - start_to[r0+r]);
    df[r] = (float)(start_from[r0+r+1] - start_from[r0+r]);
  }
  #pragma unroll
  for (int nt=0;nt<8;nt++){
    const int col = colbase + nt*16 + lr;         // 0..255
    const float bias = bn1[col];
    const float uu = uvec[col], ww = wvec[col];
    #pragma unroll
    for (int r=0;r<4;r++){
      float v = acc[nt][r] + bias + dt[r]*uu + df[r]*ww;
      v = v > 0.f ? v : 0.f;
      Hs[((wave&1)*16 + lk*4 + r)*264 + col] = (bf16_t)v;
    }
  }
  __syncthreads();

  // ---- layer 2: per wave 16 rows x 64 cols (4 n-tiles), K=256 ----
  const int cb2 = cg * 64;
  f32x4 acc2[4];
  #pragma unroll
  for (int nt=0;nt<4;nt++) acc2[nt] = (f32x4){0.f,0.f,0.f,0.f};
  #pragma unroll
  for (int kc=0;kc<8;kc++){
    bf16x8 a = *(const bf16x8*)&Hs[((wave&1)*16 + lr)*264 + kc*32 + lk*8];
    #pragma unroll
    for (int nt=0;nt<4;nt++){
      bf16x8 b = *(const bf16x8*)&Wn2b[(size_t)((kc*8 + cg*4 + nt)*64 + lane)*8];
      acc2[nt] = MFMA16(a,b,acc2[nt]);
    }
  }
  #pragma unroll
  for (int nt=0;nt<4;nt++){
    const int col = cb2 + nt*16 + lr;              // 0..127
    const float bias = bn2[col];
    #pragma unroll
    for (int r=0;r<4;r++){
      const size_t rr = (size_t)(r0 + r);
      out[rr*DD + col] = acc2[nt][r] + bias + ns[rr*DD + col];
    }
  }
}

extern "C" void kernel_launch(void* const* d_in, const int* in_sizes, int n_in,
                              void* d_out, int out_size, void* d_ws, size_t ws_size,
                              hipStream_t stream) {
  const float* ns  = (const float*)d_in[0];
  const float* ef  = (const float*)d_in[1];
  const int* from_idx = (const int*)d_in[2];
  const int* to_idx   = (const int*)d_in[3];
  const float* Wm1 = (const float*)d_in[6];  const float* bm1 = (const float*)d_in[7];
  const float* Wm2 = (const float*)d_in[8];  const float* bm2 = (const float*)d_in[9];
  const float* Wr1 = (const float*)d_in[10]; const float* br1 = (const float*)d_in[11];
  const float* Wr2 = (const float*)d_in[12]; const float* br2 = (const float*)d_in[13];
  const float* Wn1 = (const float*)d_in[14]; const float* bn1 = (const float*)d_in[15];
  const float* Wn2 = (const float*)d_in[16]; const float* bn2 = (const float*)d_in[17];

  char* ws = (char*)d_ws;
  bf16_t* Ec     = (bf16_t*)(ws);                      // 134,217,728 (phase 1)
  bf16_t* P1t    = (bf16_t*)(ws + 134217728);
  bf16_t* P2t    = (bf16_t*)(ws + 150994944);
  bf16_t* aggh_f = (bf16_t*)(ws + 167772160);
  bf16_t* aggh_r = (bf16_t*)(ws + 184549376);
  bf16_t* wpb  = (bf16_t*)(ws + 201326592);            // outside Ec
  bf16_t* wcb  = (bf16_t*)(ws + 201588736);            // outside Ec
  bf16_t* wn2b = (bf16_t*)(ws + 201654272);            // outside Ec
  int* cur_to     = (int*)(ws + 202244096);
  int* cur_from   = (int*)(ws + 202375168);
  int* start_to   = (int*)(ws + 202506240);
  int* start_from = (int*)(ws + 202637320);
  int* eid_to     = (int*)(ws + 202768400);
  int* eid_from   = (int*)(ws + 203816976);
  // phase-2 overlays inside dead Ec region (all written after the last gather_agg):
  bf16_t* attnB = (bf16_t*)(ws);                       // 8 MB
  bf16_t* nsB   = (bf16_t*)(ws + 33554432);            // 8 MB
  bf16_t* nsT   = (bf16_t*)(ws + 41943040);            // 8 MB
  bf16_t* wm2T  = (bf16_t*)(ws + 50331648);            // 128 KB
  bf16_t* wr2T  = (bf16_t*)(ws + 50462720);            // 128 KB
  bf16_t* wcat  = (bf16_t*)(ws + 50593792);            // 384 KB
  float*  uvec  = (float*) (ws + 50987008);            // 1 KB
  float*  wvec  = (float*) (ws + 50988032);            // 1 KB

  hipMemsetAsync(cur_to, 0, 2*NNODES*sizeof(int), stream);

  cvt_wp_kernel<<<128, 256, 0, stream>>>(Wm1, Wr1, wpb);
  cvt_wc_kernel<<<32, 256, 0, stream>>>(Wm1, Wr1, wcb);
  pack_wn2_kernel<<<16, 256, 0, stream>>>(Wn2, wn2b);

  hist_kernel<<<NEDGES/256, 256, 0, stream>>>(to_idx, from_idx, cur_to, cur_from);
  scan_kernel<<<1, 1024, 0, stream>>>(cur_to, start_to);
  scan_kernel<<<1, 1024, 0, stream>>>(cur_from, start_from);
  place_kernel<<<NEDGES/256, 256, 0, stream>>>(to_idx, from_idx, cur_to, cur_from, eid_to, eid_from);

  // forward: h = relu(Pa[from] + Pb[to] + Ec + bm1), aggregate at to
  proj_kernel<<<dim3(NNODES/64, 2), 256, 0, stream>>>(ns, wpb, P1t, P2t);
  ec_kernel<<<NEDGES/64, 256, 0, stream>>>(ef, wcb, eid_to, Ec);
  gather_agg_kernel<<<NNODES/4, 256, 0, stream>>>(Ec, P1t, P2t, bm1,
      start_to, eid_to, from_idx, aggh_f);

  // reverse: aggregate at from
  proj_kernel<<<dim3(NNODES/64, 2), 256, 0, stream>>>(ns, wpb + 512*128, P1t, P2t);
  ec_kernel<<<NEDGES/64, 256, 0, stream>>>(ef, wcb + 256*64, eid_from, Ec);
  gather_agg_kernel<<<NNODES/4, 256, 0, stream>>>(Ec, P1t, P2t, br1,
      start_from, eid_from, to_idx, aggh_r);

  // phase 2 prep (Ec region now dead)
  cvt_kernel<<<4096, 256, 0, stream>>>(ns, nsB, NNODES*DD);
  nst_kernel<<<NNODES/64, 256, 0, stream>>>(ns, nsT);
  w2t_kernel<<<32, 256, 0, stream>>>(Wm2, Wr2, wm2T, wr2T);
  wcat_gemm_kernel<<<dim3(4,2), 256, 0, stream>>>(Wn1, wm2T, wr2T, wcat);
  wcat_copy_kernel<<<32, 256, 0, stream>>>(Wn1, wcat);
  uw_kernel<<<1, 256, 0, stream>>>(Wn1, bm2, br2, uvec, wvec);

  attn_kernel<<<512, 256, 0, stream>>>(nsB, nsT, ns, attnB);

  node_mlp_kernel<<<NNODES/32, 256, 0, stream>>>(aggh_f, aggh_r, attnB, nsB, ns,
      wcat, bn1, uvec, wvec, start_to, start_from, wn2b, bn2, (float*)d_out);
}